// Round 2
// 1177.463 us; speedup vs baseline: 1.1545x; 1.1545x over previous
//
#include <hip/hip_runtime.h>

#define NND 50000
#define NED 800000
#define DN 128
#define DE 64
#define DKV 192
#define NH 8
#define HD 16

__device__ __forceinline__ float sane(float x) {
    return (x == x && fabsf(x) < 1e30f) ? x : 0.f;
}

// broadcast a float from a (uniform) lane of the wave
__device__ __forceinline__ float rl_f(float v, int lane) {
    return __int_as_float(__builtin_amdgcn_readlane(__float_as_int(v), lane));
}

// ---------------------------------------------------------------------------
// K1a (fast tier): Qn = X@Wq+bq -> d_out (fp32), Kn/Vn = X@W*[:128]+b* -> ws.
// 8 nodes/block, rows staged in LDS. (unchanged from baseline)
// ---------------------------------------------------------------------------
__global__ __launch_bounds__(256) void node_proj_qkv(
    const float* __restrict__ nf,
    const float* __restrict__ Wq, const float* __restrict__ bq,
    const float* __restrict__ Wk, const float* __restrict__ bk,
    const float* __restrict__ Wv, const float* __restrict__ bv,
    float* __restrict__ Qn, float* __restrict__ Kn, float* __restrict__ Vn)
{
    __shared__ alignas(16) float xs[128][8];
    const int t = threadIdx.x;
    const int nb = blockIdx.x * 8;
    {
        const int node = t >> 5;
        const int k0 = (t & 31) * 4;
        const float4 x4 = *(const float4*)(nf + (size_t)(nb + node) * DN + k0);
        xs[k0 + 0][node] = x4.x;
        xs[k0 + 1][node] = x4.y;
        xs[k0 + 2][node] = x4.z;
        xs[k0 + 3][node] = x4.w;
    }
    __syncthreads();

    const int col = t & 127;
    const int grp = t >> 7;
    float aq[4], ak[4], av[4];
    const float bqv = bq[col], bkv = bk[col], bvv = bv[col];
#pragma unroll
    for (int i = 0; i < 4; i++) { aq[i] = bqv; ak[i] = bkv; av[i] = bvv; }

#pragma unroll 4
    for (int k = 0; k < 128; k++) {
        const float wq = Wq[k * DN + col];
        const float wk = Wk[k * DN + col];   // Wk is [192,128]; rows 0..127 = node part
        const float wv = Wv[k * DN + col];
        const float4 x = *(const float4*)&xs[k][grp * 4];
        aq[0] += x.x * wq; aq[1] += x.y * wq; aq[2] += x.z * wq; aq[3] += x.w * wq;
        ak[0] += x.x * wk; ak[1] += x.y * wk; ak[2] += x.z * wk; ak[3] += x.w * wk;
        av[0] += x.x * wv; av[1] += x.y * wv; av[2] += x.z * wv; av[3] += x.w * wv;
    }
#pragma unroll
    for (int i = 0; i < 4; i++) {
        const size_t r = (size_t)(nb + grp * 4 + i) * DN + col;
        Qn[r] = aq[i]; Kn[r] = ak[i]; Vn[r] = av[i];
    }
}

// ---------------------------------------------------------------------------
// K1b (fallback tier): only Qn -> d_out (fp32)  (unchanged)
// ---------------------------------------------------------------------------
__global__ __launch_bounds__(256) void node_proj_q(
    const float* __restrict__ nf,
    const float* __restrict__ Wq, const float* __restrict__ bq,
    float* __restrict__ Qn)
{
    __shared__ alignas(16) float xs[128][8];
    const int t = threadIdx.x;
    const int nb = blockIdx.x * 8;
    {
        const int node = t >> 5;
        const int k0 = (t & 31) * 4;
        const float4 x4 = *(const float4*)(nf + (size_t)(nb + node) * DN + k0);
        xs[k0 + 0][node] = x4.x;
        xs[k0 + 1][node] = x4.y;
        xs[k0 + 2][node] = x4.z;
        xs[k0 + 3][node] = x4.w;
    }
    __syncthreads();

    const int col = t & 127;
    const int grp = t >> 7;
    float aq[4];
    const float bqv = bq[col];
#pragma unroll
    for (int i = 0; i < 4; i++) aq[i] = bqv;

#pragma unroll 4
    for (int k = 0; k < 128; k++) {
        const float wq = Wq[k * DN + col];
        const float4 x = *(const float4*)&xs[k][grp * 4];
        aq[0] += x.x * wq; aq[1] += x.y * wq; aq[2] += x.z * wq; aq[3] += x.w * wq;
    }
#pragma unroll
    for (int i = 0; i < 4; i++)
        Qn[(size_t)(nb + grp * 4 + i) * DN + col] = aq[i];
}

// ---------------------------------------------------------------------------
// CSR build: histogram of target ids, exclusive scan, scatter permutation.
// ---------------------------------------------------------------------------
__global__ __launch_bounds__(256) void edge_hist(
    const int* __restrict__ eidx, int* __restrict__ cnt)
{
    const int e = blockIdx.x * 256 + threadIdx.x;   // grid exact: NED/256
    atomicAdd(&cnt[eidx[NED + e]], 1);
}

__global__ __launch_bounds__(1024) void scan_offsets(
    const int* __restrict__ cnt, int* __restrict__ offs)
{
    __shared__ int partial[1024];
    const int t = threadIdx.x;
    constexpr int CH = (NND + 1023) / 1024;   // 49
    const int base = t * CH;
    int s = 0;
    for (int i = 0; i < CH; i++) {
        const int idx = base + i;
        if (idx < NND) s += cnt[idx];
    }
    partial[t] = s;
    __syncthreads();
    for (int off = 1; off < 1024; off <<= 1) {
        const int v = (t >= off) ? partial[t - off] : 0;
        __syncthreads();
        partial[t] += v;
        __syncthreads();
    }
    int run = (t == 0) ? 0 : partial[t - 1];   // exclusive prefix of this chunk
    for (int i = 0; i < CH; i++) {
        const int idx = base + i;
        if (idx < NND) { offs[idx] = run; run += cnt[idx]; }
    }
}

// bumps offs in place: afterwards offs[n] == segment END (exclusive), beg = end-cnt[n]
__global__ __launch_bounds__(256) void edge_scatter(
    const int* __restrict__ eidx, int* __restrict__ offs, int* __restrict__ perm)
{
    const int e = blockIdx.x * 256 + threadIdx.x;   // grid exact: NED/256
    const int pos = atomicAdd(&offs[eidx[NED + e]], 1);
    perm[pos] = e;
}

// ---------------------------------------------------------------------------
// K2 (fast tier): one wave per target node over its CSR segment.
// 8 edges/chunk; ef broadcast via v_readlane (no LDS, no barriers, no atomics).
// qo holds Qn on input; each wave overwrites ONLY its own row with the
// normalized, sanitized aggregate o.
// ---------------------------------------------------------------------------
__global__ __launch_bounds__(256) void edge_aggregate(
    const float* __restrict__ ef, const int* __restrict__ eidx,
    const int* __restrict__ cnt, const int* __restrict__ offs,
    const int* __restrict__ perm,
    const float* __restrict__ Wk, const float* __restrict__ Wv,
    const float* __restrict__ Kn, const float* __restrict__ Vn,
    float* qo)
{
    const int t = threadIdx.x;
    const int w = t >> 6;
    const int l = t & 63;
    const int node = blockIdx.x * 4 + w;     // grid exact: NND/4

    const int end = offs[node];              // post-scatter: segment end
    const int beg = end - cnt[node];

    const float2 q2 = *(const float2*)(qo + (size_t)node * DN + 2 * l);

    const float* __restrict__ WkB = Wk + 128 * DN;   // edge-feature rows of Wk [192,128]
    const float* __restrict__ WvB = Wv + 128 * DN;

    float acc0 = 0.f, acc1 = 0.f, segacc = 0.f;

    for (int base = beg; base < end; base += 8) {
        // lane layout: 8 lanes per edge; lane (e*8+q) holds ef[edge e][q*8 .. q*8+7]
        const int myE = min(base + (l >> 3), end - 1);   // clamp padded slots to a real edge
        const int pe = perm[myE];
        const int q8 = (l & 7) * 8;
        const float4 A = *(const float4*)(ef + (size_t)pe * DE + q8);
        const float4 B = *(const float4*)(ef + (size_t)pe * DE + q8 + 4);

        int src[8];
#pragma unroll
        for (int e = 0; e < 8; e++)
            src[e] = eidx[__builtin_amdgcn_readlane(pe, e * 8)];

        float accK[8][2], accV[8][2];
#pragma unroll
        for (int e = 0; e < 8; e++) {
            accK[e][0] = 0.f; accK[e][1] = 0.f;
            accV[e][0] = 0.f; accV[e][1] = 0.f;
        }

        // Ke/Ve edge part: acc[e][c] += ef[e][k] * W[k][2l+c], k = qq*8 + c_idx
#define KSTEP(c, comp) { \
        const int kk = qq * 8 + (c); \
        const float2 wk2 = *(const float2*)(WkB + kk * DN + 2 * l); \
        const float2 wv2 = *(const float2*)(WvB + kk * DN + 2 * l); \
        const float b0 = rl_f((comp), 0 * 8 + qq); \
        const float b1 = rl_f((comp), 1 * 8 + qq); \
        const float b2 = rl_f((comp), 2 * 8 + qq); \
        const float b3 = rl_f((comp), 3 * 8 + qq); \
        const float b4 = rl_f((comp), 4 * 8 + qq); \
        const float b5 = rl_f((comp), 5 * 8 + qq); \
        const float b6 = rl_f((comp), 6 * 8 + qq); \
        const float b7 = rl_f((comp), 7 * 8 + qq); \
        accK[0][0] += b0 * wk2.x; accK[0][1] += b0 * wk2.y; accV[0][0] += b0 * wv2.x; accV[0][1] += b0 * wv2.y; \
        accK[1][0] += b1 * wk2.x; accK[1][1] += b1 * wk2.y; accV[1][0] += b1 * wv2.x; accV[1][1] += b1 * wv2.y; \
        accK[2][0] += b2 * wk2.x; accK[2][1] += b2 * wk2.y; accV[2][0] += b2 * wv2.x; accV[2][1] += b2 * wv2.y; \
        accK[3][0] += b3 * wk2.x; accK[3][1] += b3 * wk2.y; accV[3][0] += b3 * wv2.x; accV[3][1] += b3 * wv2.y; \
        accK[4][0] += b4 * wk2.x; accK[4][1] += b4 * wk2.y; accV[4][0] += b4 * wv2.x; accV[4][1] += b4 * wv2.y; \
        accK[5][0] += b5 * wk2.x; accK[5][1] += b5 * wk2.y; accV[5][0] += b5 * wv2.x; accV[5][1] += b5 * wv2.y; \
        accK[6][0] += b6 * wk2.x; accK[6][1] += b6 * wk2.y; accV[6][0] += b6 * wv2.x; accV[6][1] += b6 * wv2.y; \
        accK[7][0] += b7 * wk2.x; accK[7][1] += b7 * wk2.y; accV[7][0] += b7 * wv2.x; accV[7][1] += b7 * wv2.y; }

#pragma unroll 2
        for (int qq = 0; qq < 8; qq++) {
            KSTEP(0, A.x) KSTEP(1, A.y) KSTEP(2, A.z) KSTEP(3, A.w)
            KSTEP(4, B.x) KSTEP(5, B.y) KSTEP(6, B.z) KSTEP(7, B.w)
        }
#undef KSTEP

#pragma unroll
        for (int e = 0; e < 8; e++) {
            const float2 kn2 = *(const float2*)(Kn + (size_t)src[e] * DN + 2 * l);
            float part = q2.x * (kn2.x + accK[e][0]) + q2.y * (kn2.y + accK[e][1]);
            part += __shfl_xor(part, 1);
            part += __shfl_xor(part, 2);
            part += __shfl_xor(part, 4);   // 8-lane head group now holds a[e,h]
            const float arg = fminf(fmaxf(part * 0.25f, -60.f), 60.f);   // 1/sqrt(16)
            const float p = (base + e < end) ? __expf(arg) : 0.f;        // mask padded edges
            const float2 vn2 = *(const float2*)(Vn + (size_t)src[e] * DN + 2 * l);
            acc0 += p * (vn2.x + accV[e][0]);
            acc1 += p * (vn2.y + accV[e][1]);
            segacc += p;
        }
    }

    const float r = (segacc > 0.f) ? 1.f / segacc : 0.f;   // deg==0 -> zeros
    float* orow = qo + (size_t)node * DN + 2 * l;
    orow[0] = sane(acc0 * r);
    orow[1] = sane(acc1 * r);
}

// ---------------------------------------------------------------------------
// K2b (fallback tier, needs only 27.2MB ws): recompute full K/V per edge,
// scatter with atomics. (unchanged from baseline)
// ---------------------------------------------------------------------------
__global__ __launch_bounds__(256) void edge_pass_full(
    const float* __restrict__ nf, const float* __restrict__ ef,
    const int* __restrict__ eidx,
    const float* __restrict__ Wk, const float* __restrict__ bk,
    const float* __restrict__ Wv, const float* __restrict__ bv,
    const float* __restrict__ Qn,
    float* __restrict__ o_un, float* __restrict__ seg)
{
    __shared__ alignas(16) float kvs[4][192][4];
    const int t = threadIdx.x;
    const int w = t >> 6;
    const int l = t & 63;
    const int eb = blockIdx.x * 16 + w * 4;

    int src[4], tgt[4];
#pragma unroll
    for (int e = 0; e < 4; e++) {
        src[e] = eidx[eb + e];
        tgt[e] = eidx[NED + eb + e];
    }

#pragma unroll
    for (int it = 0; it < 3; it++) {
        const int idx = it * 64 + l;
        const int e = idx / 48;
        const int pos = (idx % 48) * 4;
        const float* p = (pos < 128)
            ? nf + (size_t)src[e] * DN + pos
            : ef + (size_t)(eb + e) * DE + (pos - 128);
        const float4 x4 = *(const float4*)p;
        kvs[w][pos + 0][e] = x4.x;
        kvs[w][pos + 1][e] = x4.y;
        kvs[w][pos + 2][e] = x4.z;
        kvs[w][pos + 3][e] = x4.w;
    }
    __syncthreads();

    const float bk0 = bk[2 * l], bk1 = bk[2 * l + 1];
    const float bv0 = bv[2 * l], bv1 = bv[2 * l + 1];
    float accK[4][2] = {{bk0,bk1},{bk0,bk1},{bk0,bk1},{bk0,bk1}};
    float accV[4][2] = {{bv0,bv1},{bv0,bv1},{bv0,bv1},{bv0,bv1}};

#pragma unroll 4
    for (int k = 0; k < DKV; k++) {
        const float4 e4 = *(const float4*)&kvs[w][k][0];
        const float2 wk2 = *(const float2*)(Wk + k * DN + 2 * l);
        const float2 wv2 = *(const float2*)(Wv + k * DN + 2 * l);
        accK[0][0] += e4.x * wk2.x; accK[0][1] += e4.x * wk2.y;
        accK[1][0] += e4.y * wk2.x; accK[1][1] += e4.y * wk2.y;
        accK[2][0] += e4.z * wk2.x; accK[2][1] += e4.z * wk2.y;
        accK[3][0] += e4.w * wk2.x; accK[3][1] += e4.w * wk2.y;
        accV[0][0] += e4.x * wv2.x; accV[0][1] += e4.x * wv2.y;
        accV[1][0] += e4.y * wv2.x; accV[1][1] += e4.y * wv2.y;
        accV[2][0] += e4.z * wv2.x; accV[2][1] += e4.z * wv2.y;
        accV[3][0] += e4.w * wv2.x; accV[3][1] += e4.w * wv2.y;
    }

    const int h = l >> 3;
#pragma unroll
    for (int e = 0; e < 4; e++) {
        const float2 q2 = *(const float2*)(Qn + (size_t)tgt[e] * DN + 2 * l);
        float part = q2.x * accK[e][0] + q2.y * accK[e][1];
        part += __shfl_xor(part, 1);
        part += __shfl_xor(part, 2);
        part += __shfl_xor(part, 4);
        float arg = fminf(fmaxf(part * 0.25f, -60.f), 60.f);
        const float p = __expf(arg);

        atomicAdd(&o_un[(size_t)tgt[e] * DN + 2 * l],     p * accV[e][0]);
        atomicAdd(&o_un[(size_t)tgt[e] * DN + 2 * l + 1], p * accV[e][1]);
        if ((l & 7) == 0) atomicAdd(&seg[tgt[e] * NH + h], p);
    }
}

// ---------------------------------------------------------------------------
// K3: out = sanitize(o / seg) @ Wo + bo. seg == nullptr -> o already
// normalized (fast tier; o aliases out, block reads its 8 rows before the
// barrier and writes only those rows after it).
// ---------------------------------------------------------------------------
__global__ __launch_bounds__(256) void out_proj(
    const float* o_un, const float* __restrict__ seg,
    const float* __restrict__ Wo, const float* __restrict__ bo,
    float* out)
{
    __shared__ alignas(16) float xs[128][8];
    const int t = threadIdx.x;
    const int nb = blockIdx.x * 8;
    {
        const int node = t >> 5;
        const int k0 = (t & 31) * 4;
        const float4 v = *(const float4*)(o_un + (size_t)(nb + node) * DN + k0);
        float r = 1.f;
        if (seg) {
            const float s = seg[(nb + node) * NH + (k0 >> 4)];
            r = (s > 0.f) ? 1.f / s : 0.f;
        }
        xs[k0 + 0][node] = sane(v.x * r);
        xs[k0 + 1][node] = sane(v.y * r);
        xs[k0 + 2][node] = sane(v.z * r);
        xs[k0 + 3][node] = sane(v.w * r);
    }
    __syncthreads();

    const int col = t & 127;
    const int grp = t >> 7;
    float acc[4];
    const float b = bo[col];
#pragma unroll
    for (int i = 0; i < 4; i++) acc[i] = b;

#pragma unroll 4
    for (int k = 0; k < 128; k++) {
        const float wo = Wo[k * DN + col];
        const float4 x = *(const float4*)&xs[k][grp * 4];
        acc[0] += x.x * wo; acc[1] += x.y * wo; acc[2] += x.z * wo; acc[3] += x.w * wo;
    }
#pragma unroll
    for (int i = 0; i < 4; i++)
        out[(size_t)(nb + grp * 4 + i) * DN + col] = acc[i];
}

// ---------------------------------------------------------------------------
extern "C" void kernel_launch(void* const* d_in, const int* in_sizes, int n_in,
                              void* d_out, int out_size, void* d_ws, size_t ws_size,
                              hipStream_t stream) {
    const float* nf   = (const float*)d_in[0];
    const float* ef   = (const float*)d_in[1];
    const int*   eidx = (const int*)d_in[2];
    const float* Wq   = (const float*)d_in[3];
    const float* bq   = (const float*)d_in[4];
    const float* Wk   = (const float*)d_in[5];
    const float* bk   = (const float*)d_in[6];
    const float* Wv   = (const float*)d_in[7];
    const float* bv   = (const float*)d_in[8];
    const float* Wo   = (const float*)d_in[9];
    const float* bo   = (const float*)d_in[10];
    float* out = (float*)d_out;

    // Qn lives in d_out; edge_aggregate overwrites it in place with normalized o,
    // out_proj then overwrites with the final output.
    float* Qn = out;

    const size_t tabBytes = (size_t)NND * DN * sizeof(float);                  // 25.6 MB
    const size_t csrBytes = 2 * tabBytes
                          + (size_t)(2 * NND + NED) * sizeof(int);             // 54.8 MB
    const size_t accBytes = tabBytes + (size_t)NND * NH * sizeof(float);       // 27.2 MB

    if (ws_size >= csrBytes) {
        float* Kn  = (float*)d_ws;
        float* Vn  = Kn + (size_t)NND * DN;
        int*   cnt = (int*)(Vn + (size_t)NND * DN);
        int*   offs= cnt + NND;
        int*   perm= offs + NND;
        hipMemsetAsync(cnt, 0, NND * sizeof(int), stream);
        node_proj_qkv<<<NND / 8, 256, 0, stream>>>(nf, Wq, bq, Wk, bk, Wv, bv, Qn, Kn, Vn);
        edge_hist<<<NED / 256, 256, 0, stream>>>(eidx, cnt);
        scan_offsets<<<1, 1024, 0, stream>>>(cnt, offs);
        edge_scatter<<<NED / 256, 256, 0, stream>>>(eidx, offs, perm);
        edge_aggregate<<<NND / 4, 256, 0, stream>>>(ef, eidx, cnt, offs, perm,
                                                    Wk, Wv, Kn, Vn, Qn);
        out_proj<<<NND / 8, 256, 0, stream>>>(Qn, nullptr, Wo, bo, out);
    } else {
        float* o_un = (float*)d_ws;
        float* seg  = o_un + (size_t)NND * DN;
        hipMemsetAsync(o_un, 0, accBytes, stream);
        node_proj_q<<<NND / 8, 256, 0, stream>>>(nf, Wq, bq, Qn);
        edge_pass_full<<<NED / 16, 256, 0, stream>>>(nf, ef, eidx, Wk, bk, Wv, bv, Qn, o_un, seg);
        out_proj<<<NND / 8, 256, 0, stream>>>(o_un, seg, Wo, bo, out);
    }
}

// Round 3
// 871.907 us; speedup vs baseline: 1.5590x; 1.3504x over previous
//
#include <hip/hip_runtime.h>

#define NND 50000
#define NED 800000
#define DN 128
#define DE 64
#define DKV 192
#define NH 8
#define HD 16

__device__ __forceinline__ float sane(float x) {
    return (x == x && fabsf(x) < 1e30f) ? x : 0.f;
}

// ---------------------------------------------------------------------------
// K1a (fast tier): Qn = X@Wq+bq -> d_out (fp32), Kn/Vn = X@W*[:128]+b* -> ws.
// 8 nodes/block, rows staged in LDS. (unchanged)
// ---------------------------------------------------------------------------
__global__ __launch_bounds__(256) void node_proj_qkv(
    const float* __restrict__ nf,
    const float* __restrict__ Wq, const float* __restrict__ bq,
    const float* __restrict__ Wk, const float* __restrict__ bk,
    const float* __restrict__ Wv, const float* __restrict__ bv,
    float* __restrict__ Qn, float* __restrict__ Kn, float* __restrict__ Vn)
{
    __shared__ alignas(16) float xs[128][8];
    const int t = threadIdx.x;
    const int nb = blockIdx.x * 8;
    {
        const int node = t >> 5;
        const int k0 = (t & 31) * 4;
        const float4 x4 = *(const float4*)(nf + (size_t)(nb + node) * DN + k0);
        xs[k0 + 0][node] = x4.x;
        xs[k0 + 1][node] = x4.y;
        xs[k0 + 2][node] = x4.z;
        xs[k0 + 3][node] = x4.w;
    }
    __syncthreads();

    const int col = t & 127;
    const int grp = t >> 7;
    float aq[4], ak[4], av[4];
    const float bqv = bq[col], bkv = bk[col], bvv = bv[col];
#pragma unroll
    for (int i = 0; i < 4; i++) { aq[i] = bqv; ak[i] = bkv; av[i] = bvv; }

#pragma unroll 4
    for (int k = 0; k < 128; k++) {
        const float wq = Wq[k * DN + col];
        const float wk = Wk[k * DN + col];   // Wk is [192,128]; rows 0..127 = node part
        const float wv = Wv[k * DN + col];
        const float4 x = *(const float4*)&xs[k][grp * 4];
        aq[0] += x.x * wq; aq[1] += x.y * wq; aq[2] += x.z * wq; aq[3] += x.w * wq;
        ak[0] += x.x * wk; ak[1] += x.y * wk; ak[2] += x.z * wk; ak[3] += x.w * wk;
        av[0] += x.x * wv; av[1] += x.y * wv; av[2] += x.z * wv; av[3] += x.w * wv;
    }
#pragma unroll
    for (int i = 0; i < 4; i++) {
        const size_t r = (size_t)(nb + grp * 4 + i) * DN + col;
        Qn[r] = aq[i]; Kn[r] = ak[i]; Vn[r] = av[i];
    }
}

// ---------------------------------------------------------------------------
// K1b (fallback tier): only Qn -> d_out (fp32)  (unchanged)
// ---------------------------------------------------------------------------
__global__ __launch_bounds__(256) void node_proj_q(
    const float* __restrict__ nf,
    const float* __restrict__ Wq, const float* __restrict__ bq,
    float* __restrict__ Qn)
{
    __shared__ alignas(16) float xs[128][8];
    const int t = threadIdx.x;
    const int nb = blockIdx.x * 8;
    {
        const int node = t >> 5;
        const int k0 = (t & 31) * 4;
        const float4 x4 = *(const float4*)(nf + (size_t)(nb + node) * DN + k0);
        xs[k0 + 0][node] = x4.x;
        xs[k0 + 1][node] = x4.y;
        xs[k0 + 2][node] = x4.z;
        xs[k0 + 3][node] = x4.w;
    }
    __syncthreads();

    const int col = t & 127;
    const int grp = t >> 7;
    float aq[4];
    const float bqv = bq[col];
#pragma unroll
    for (int i = 0; i < 4; i++) aq[i] = bqv;

#pragma unroll 4
    for (int k = 0; k < 128; k++) {
        const float wq = Wq[k * DN + col];
        const float4 x = *(const float4*)&xs[k][grp * 4];
        aq[0] += x.x * wq; aq[1] += x.y * wq; aq[2] += x.z * wq; aq[3] += x.w * wq;
    }
#pragma unroll
    for (int i = 0; i < 4; i++)
        Qn[(size_t)(nb + grp * 4 + i) * DN + col] = aq[i];
}

// ---------------------------------------------------------------------------
// CSR build: histogram of target ids, exclusive scan, scatter permutation.
// edge_scatter also emits srcp[pos] = src-node of the permuted edge, so the
// aggregate kernel never dereferences eidx.
// ---------------------------------------------------------------------------
__global__ __launch_bounds__(256) void edge_hist(
    const int* __restrict__ eidx, int* __restrict__ cnt)
{
    const int e = blockIdx.x * 256 + threadIdx.x;   // grid exact: NED/256
    atomicAdd(&cnt[eidx[NED + e]], 1);
}

__global__ __launch_bounds__(1024) void scan_offsets(
    const int* __restrict__ cnt, int* __restrict__ offs)
{
    __shared__ int partial[1024];
    const int t = threadIdx.x;
    constexpr int CH = (NND + 1023) / 1024;   // 49
    const int base = t * CH;
    int s = 0;
    for (int i = 0; i < CH; i++) {
        const int idx = base + i;
        if (idx < NND) s += cnt[idx];
    }
    partial[t] = s;
    __syncthreads();
    for (int off = 1; off < 1024; off <<= 1) {
        const int v = (t >= off) ? partial[t - off] : 0;
        __syncthreads();
        partial[t] += v;
        __syncthreads();
    }
    int run = (t == 0) ? 0 : partial[t - 1];   // exclusive prefix of this chunk
    for (int i = 0; i < CH; i++) {
        const int idx = base + i;
        if (idx < NND) { offs[idx] = run; run += cnt[idx]; }
    }
}

// bumps offs in place: afterwards offs[n] == segment END (exclusive), beg = end-cnt[n]
__global__ __launch_bounds__(256) void edge_scatter(
    const int* __restrict__ eidx, int* __restrict__ offs,
    int* __restrict__ perm, int* __restrict__ srcp)
{
    const int e = blockIdx.x * 256 + threadIdx.x;   // grid exact: NED/256
    const int pos = atomicAdd(&offs[eidx[NED + e]], 1);
    perm[pos] = e;
    srcp[pos] = eidx[e];
}

// ---------------------------------------------------------------------------
// K2 (fast tier): one wave per target node over its CSR segment.
// Factorized edge math:
//   logit[e,h] = 0.25*( q.Kn[src] + sum_k Qt[h,k]*ef[e,k] ),
//     Qt[h,k] = sum_{c in head h} q[c]*WkB[k,c]   (per-node prologue)
//   o_edge[c] = sum_k WvB[k,c]*G[h(c),k],
//     G[h,k]  = sum_e p[e,h]*ef[e,k]              (per-node register accum)
// Lane (h=l>>3, j=l&7) owns k-slice j*8..j*8+7 of Qt/G and cols 2l,2l+1.
// ef staged per-wave in LDS (wave-private, no barriers, no atomics).
// ---------------------------------------------------------------------------
__global__ __launch_bounds__(256) void edge_aggregate(
    const float* __restrict__ ef,
    const int* __restrict__ cnt, const int* __restrict__ offs,
    const int* __restrict__ perm, const int* __restrict__ srcp,
    const float* __restrict__ Wk, const float* __restrict__ Wv,
    const float* __restrict__ Kn, const float* __restrict__ Vn,
    float* qo)
{
    __shared__ alignas(16) float efs[4][8][64];   // [wave][edge][k]
    const int t = threadIdx.x;
    const int w = t >> 6;
    const int l = t & 63;
    const int j = l & 7;
    const int node = blockIdx.x * 4 + w;          // grid exact: NND/4

    const int end = offs[node];                   // post-scatter: segment end
    const int beg = end - cnt[node];

    const float* __restrict__ WkB = Wk + 128 * DN;   // edge-feature rows of Wk [192,128]
    const float* __restrict__ WvB = Wv + 128 * DN;

    const float2 q2 = *(const float2*)(qo + (size_t)node * DN + 2 * l);

    // ---- prologue: Qt[h, j*8+i] into qt[i] (coalesced WkB row reads) ----
    float qt[8];
#pragma unroll
    for (int i = 0; i < 8; i++) qt[i] = 0.f;
#pragma unroll 16
    for (int k = 0; k < 64; k++) {
        const float2 wk2 = *(const float2*)(WkB + k * DN + 2 * l);
        float part = q2.x * wk2.x + q2.y * wk2.y;
        part += __shfl_xor(part, 1);
        part += __shfl_xor(part, 2);
        part += __shfl_xor(part, 4);              // sum over head's 16 cols
        if (j == (k >> 3)) qt[k & 7] = part;
    }

    float acc0 = 0.f, acc1 = 0.f, segacc = 0.f;
    float gt[8];
#pragma unroll
    for (int i = 0; i < 8; i++) gt[i] = 0.f;

    for (int base = beg; base < end; base += 8) {
        const int myE = min(base + (l >> 3), end - 1);   // clamp padded slots
        const int pe = perm[myE];
        // stage ef chunk: lane stages its edge's k-slice j*8..j*8+7
        const float4 A = *(const float4*)(ef + (size_t)pe * DE + j * 8);
        const float4 B = *(const float4*)(ef + (size_t)pe * DE + j * 8 + 4);
        *(float4*)&efs[w][l >> 3][j * 8]     = A;
        *(float4*)&efs[w][l >> 3][j * 8 + 4] = B;

        const int mySrc = srcp[myE];

#pragma unroll
        for (int e = 0; e < 8; e++) {
            const int se = __builtin_amdgcn_readlane(mySrc, e * 8);
            const float4 efA = *(const float4*)&efs[w][e][j * 8];
            const float4 efB = *(const float4*)&efs[w][e][j * 8 + 4];
            const float2 kn2 = *(const float2*)(Kn + (size_t)se * DN + 2 * l);
            float part = q2.x * kn2.x + q2.y * kn2.y
                       + efA.x * qt[0] + efA.y * qt[1] + efA.z * qt[2] + efA.w * qt[3]
                       + efB.x * qt[4] + efB.y * qt[5] + efB.z * qt[6] + efB.w * qt[7];
            part += __shfl_xor(part, 1);
            part += __shfl_xor(part, 2);
            part += __shfl_xor(part, 4);          // logit[e,h] on 8-lane head group
            const float arg = fminf(fmaxf(part * 0.25f, -60.f), 60.f);  // 1/sqrt(16)
            const float p = (base + e < end) ? __expf(arg) : 0.f;       // mask pads
            const float2 vn2 = *(const float2*)(Vn + (size_t)se * DN + 2 * l);
            acc0 += p * vn2.x;
            acc1 += p * vn2.y;
            segacc += p;
            gt[0] += p * efA.x; gt[1] += p * efA.y; gt[2] += p * efA.z; gt[3] += p * efA.w;
            gt[4] += p * efB.x; gt[5] += p * efB.y; gt[6] += p * efB.z; gt[7] += p * efB.w;
        }
    }

    // ---- epilogue: o_edge = G @ WvB (G slices broadcast via bpermute) ----
    float oe0 = 0.f, oe1 = 0.f;
#pragma unroll 16
    for (int k = 0; k < 64; k++) {
        const float g = __shfl(gt[k & 7], (l & 56) | (k >> 3));
        const float2 wv2 = *(const float2*)(WvB + k * DN + 2 * l);
        oe0 += g * wv2.x;
        oe1 += g * wv2.y;
    }
    acc0 += oe0;
    acc1 += oe1;

    const float r = (segacc > 0.f) ? 1.f / segacc : 0.f;   // deg==0 -> zeros
    float* orow = qo + (size_t)node * DN + 2 * l;
    orow[0] = sane(acc0 * r);
    orow[1] = sane(acc1 * r);
}

// ---------------------------------------------------------------------------
// K2b (fallback tier, needs only 27.2MB ws): recompute full K/V per edge,
// scatter with atomics. (unchanged)
// ---------------------------------------------------------------------------
__global__ __launch_bounds__(256) void edge_pass_full(
    const float* __restrict__ nf, const float* __restrict__ ef,
    const int* __restrict__ eidx,
    const float* __restrict__ Wk, const float* __restrict__ bk,
    const float* __restrict__ Wv, const float* __restrict__ bv,
    const float* __restrict__ Qn,
    float* __restrict__ o_un, float* __restrict__ seg)
{
    __shared__ alignas(16) float kvs[4][192][4];
    const int t = threadIdx.x;
    const int w = t >> 6;
    const int l = t & 63;
    const int eb = blockIdx.x * 16 + w * 4;

    int src[4], tgt[4];
#pragma unroll
    for (int e = 0; e < 4; e++) {
        src[e] = eidx[eb + e];
        tgt[e] = eidx[NED + eb + e];
    }

#pragma unroll
    for (int it = 0; it < 3; it++) {
        const int idx = it * 64 + l;
        const int e = idx / 48;
        const int pos = (idx % 48) * 4;
        const float* p = (pos < 128)
            ? nf + (size_t)src[e] * DN + pos
            : ef + (size_t)(eb + e) * DE + (pos - 128);
        const float4 x4 = *(const float4*)p;
        kvs[w][pos + 0][e] = x4.x;
        kvs[w][pos + 1][e] = x4.y;
        kvs[w][pos + 2][e] = x4.z;
        kvs[w][pos + 3][e] = x4.w;
    }
    __syncthreads();

    const float bk0 = bk[2 * l], bk1 = bk[2 * l + 1];
    const float bv0 = bv[2 * l], bv1 = bv[2 * l + 1];
    float accK[4][2] = {{bk0,bk1},{bk0,bk1},{bk0,bk1},{bk0,bk1}};
    float accV[4][2] = {{bv0,bv1},{bv0,bv1},{bv0,bv1},{bv0,bv1}};

#pragma unroll 4
    for (int k = 0; k < DKV; k++) {
        const float4 e4 = *(const float4*)&kvs[w][k][0];
        const float2 wk2 = *(const float2*)(Wk + k * DN + 2 * l);
        const float2 wv2 = *(const float2*)(Wv + k * DN + 2 * l);
        accK[0][0] += e4.x * wk2.x; accK[0][1] += e4.x * wk2.y;
        accK[1][0] += e4.y * wk2.x; accK[1][1] += e4.y * wk2.y;
        accK[2][0] += e4.z * wk2.x; accK[2][1] += e4.z * wk2.y;
        accK[3][0] += e4.w * wk2.x; accK[3][1] += e4.w * wk2.y;
        accV[0][0] += e4.x * wv2.x; accV[0][1] += e4.x * wv2.y;
        accV[1][0] += e4.y * wv2.x; accV[1][1] += e4.y * wv2.y;
        accV[2][0] += e4.z * wv2.x; accV[2][1] += e4.z * wv2.y;
        accV[3][0] += e4.w * wv2.x; accV[3][1] += e4.w * wv2.y;
    }

    const int h = l >> 3;
#pragma unroll
    for (int e = 0; e < 4; e++) {
        const float2 q2 = *(const float2*)(Qn + (size_t)tgt[e] * DN + 2 * l);
        float part = q2.x * accK[e][0] + q2.y * accK[e][1];
        part += __shfl_xor(part, 1);
        part += __shfl_xor(part, 2);
        part += __shfl_xor(part, 4);
        float arg = fminf(fmaxf(part * 0.25f, -60.f), 60.f);
        const float p = __expf(arg);

        atomicAdd(&o_un[(size_t)tgt[e] * DN + 2 * l],     p * accV[e][0]);
        atomicAdd(&o_un[(size_t)tgt[e] * DN + 2 * l + 1], p * accV[e][1]);
        if ((l & 7) == 0) atomicAdd(&seg[tgt[e] * NH + h], p);
    }
}

// ---------------------------------------------------------------------------
// K3: out = sanitize(o / seg) @ Wo + bo. seg == nullptr -> o already
// normalized (fast tier; o aliases out, block reads its 8 rows before the
// barrier and writes only those rows after it).
// ---------------------------------------------------------------------------
__global__ __launch_bounds__(256) void out_proj(
    const float* o_un, const float* __restrict__ seg,
    const float* __restrict__ Wo, const float* __restrict__ bo,
    float* out)
{
    __shared__ alignas(16) float xs[128][8];
    const int t = threadIdx.x;
    const int nb = blockIdx.x * 8;
    {
        const int node = t >> 5;
        const int k0 = (t & 31) * 4;
        const float4 v = *(const float4*)(o_un + (size_t)(nb + node) * DN + k0);
        float r = 1.f;
        if (seg) {
            const float s = seg[(nb + node) * NH + (k0 >> 4)];
            r = (s > 0.f) ? 1.f / s : 0.f;
        }
        xs[k0 + 0][node] = sane(v.x * r);
        xs[k0 + 1][node] = sane(v.y * r);
        xs[k0 + 2][node] = sane(v.z * r);
        xs[k0 + 3][node] = sane(v.w * r);
    }
    __syncthreads();

    const int col = t & 127;
    const int grp = t >> 7;
    float acc[4];
    const float b = bo[col];
#pragma unroll
    for (int i = 0; i < 4; i++) acc[i] = b;

#pragma unroll 4
    for (int k = 0; k < 128; k++) {
        const float wo = Wo[k * DN + col];
        const float4 x = *(const float4*)&xs[k][grp * 4];
        acc[0] += x.x * wo; acc[1] += x.y * wo; acc[2] += x.z * wo; acc[3] += x.w * wo;
    }
#pragma unroll
    for (int i = 0; i < 4; i++)
        out[(size_t)(nb + grp * 4 + i) * DN + col] = acc[i];
}

// ---------------------------------------------------------------------------
extern "C" void kernel_launch(void* const* d_in, const int* in_sizes, int n_in,
                              void* d_out, int out_size, void* d_ws, size_t ws_size,
                              hipStream_t stream) {
    const float* nf   = (const float*)d_in[0];
    const float* ef   = (const float*)d_in[1];
    const int*   eidx = (const int*)d_in[2];
    const float* Wq   = (const float*)d_in[3];
    const float* bq   = (const float*)d_in[4];
    const float* Wk   = (const float*)d_in[5];
    const float* bk   = (const float*)d_in[6];
    const float* Wv   = (const float*)d_in[7];
    const float* bv   = (const float*)d_in[8];
    const float* Wo   = (const float*)d_in[9];
    const float* bo   = (const float*)d_in[10];
    float* out = (float*)d_out;

    // Qn lives in d_out; edge_aggregate overwrites it in place with normalized o,
    // out_proj then overwrites with the final output.
    float* Qn = out;

    const size_t tabBytes = (size_t)NND * DN * sizeof(float);                  // 25.6 MB
    const size_t csrBytes = 2 * tabBytes
                          + (size_t)(2 * NND + 2 * NED) * sizeof(int);         // 58.0 MB
    const size_t accBytes = tabBytes + (size_t)NND * NH * sizeof(float);       // 27.2 MB

    if (ws_size >= csrBytes) {
        float* Kn  = (float*)d_ws;
        float* Vn  = Kn + (size_t)NND * DN;
        int*   cnt = (int*)(Vn + (size_t)NND * DN);
        int*   offs= cnt + NND;
        int*   perm= offs + NND;
        int*   srcp= perm + NED;
        hipMemsetAsync(cnt, 0, NND * sizeof(int), stream);
        node_proj_qkv<<<NND / 8, 256, 0, stream>>>(nf, Wq, bq, Wk, bk, Wv, bv, Qn, Kn, Vn);
        edge_hist<<<NED / 256, 256, 0, stream>>>(eidx, cnt);
        scan_offsets<<<1, 1024, 0, stream>>>(cnt, offs);
        edge_scatter<<<NED / 256, 256, 0, stream>>>(eidx, offs, perm, srcp);
        edge_aggregate<<<NND / 4, 256, 0, stream>>>(ef, cnt, offs, perm, srcp,
                                                    Wk, Wv, Kn, Vn, Qn);
        out_proj<<<NND / 8, 256, 0, stream>>>(Qn, nullptr, Wo, bo, out);
    } else {
        float* o_un = (float*)d_ws;
        float* seg  = o_un + (size_t)NND * DN;
        hipMemsetAsync(o_un, 0, accBytes, stream);
        node_proj_q<<<NND / 8, 256, 0, stream>>>(nf, Wq, bq, Qn);
        edge_pass_full<<<NED / 16, 256, 0, stream>>>(nf, ef, eidx, Wk, bk, Wv, bv, Qn, o_un, seg);
        out_proj<<<NND / 8, 256, 0, stream>>>(o_un, seg, Wo, bo, out);
    }
}

// Round 4
// 865.909 us; speedup vs baseline: 1.5698x; 1.0069x over previous
//
#include <hip/hip_runtime.h>

#define NND 50000
#define NED 800000
#define DN 128
#define DE 64
#define DKV 192
#define NH 8
#define HD 16

__device__ __forceinline__ float sane(float x) {
    return (x == x && fabsf(x) < 1e30f) ? x : 0.f;
}

// ---------------------------------------------------------------------------
// K1a (fast tier): Qn = X@Wq+bq -> d_out (fp32), Kn/Vn = X@W*[:128]+b* -> ws.
// 8 nodes/block, rows staged in LDS. (unchanged)
// ---------------------------------------------------------------------------
__global__ __launch_bounds__(256) void node_proj_qkv(
    const float* __restrict__ nf,
    const float* __restrict__ Wq, const float* __restrict__ bq,
    const float* __restrict__ Wk, const float* __restrict__ bk,
    const float* __restrict__ Wv, const float* __restrict__ bv,
    float* __restrict__ Qn, float* __restrict__ Kn, float* __restrict__ Vn)
{
    __shared__ alignas(16) float xs[128][8];
    const int t = threadIdx.x;
    const int nb = blockIdx.x * 8;
    {
        const int node = t >> 5;
        const int k0 = (t & 31) * 4;
        const float4 x4 = *(const float4*)(nf + (size_t)(nb + node) * DN + k0);
        xs[k0 + 0][node] = x4.x;
        xs[k0 + 1][node] = x4.y;
        xs[k0 + 2][node] = x4.z;
        xs[k0 + 3][node] = x4.w;
    }
    __syncthreads();

    const int col = t & 127;
    const int grp = t >> 7;
    float aq[4], ak[4], av[4];
    const float bqv = bq[col], bkv = bk[col], bvv = bv[col];
#pragma unroll
    for (int i = 0; i < 4; i++) { aq[i] = bqv; ak[i] = bkv; av[i] = bvv; }

#pragma unroll 4
    for (int k = 0; k < 128; k++) {
        const float wq = Wq[k * DN + col];
        const float wk = Wk[k * DN + col];   // Wk is [192,128]; rows 0..127 = node part
        const float wv = Wv[k * DN + col];
        const float4 x = *(const float4*)&xs[k][grp * 4];
        aq[0] += x.x * wq; aq[1] += x.y * wq; aq[2] += x.z * wq; aq[3] += x.w * wq;
        ak[0] += x.x * wk; ak[1] += x.y * wk; ak[2] += x.z * wk; ak[3] += x.w * wk;
        av[0] += x.x * wv; av[1] += x.y * wv; av[2] += x.z * wv; av[3] += x.w * wv;
    }
#pragma unroll
    for (int i = 0; i < 4; i++) {
        const size_t r = (size_t)(nb + grp * 4 + i) * DN + col;
        Qn[r] = aq[i]; Kn[r] = ak[i]; Vn[r] = av[i];
    }
}

// ---------------------------------------------------------------------------
// K1b (fallback tier): only Qn -> d_out (fp32)  (unchanged)
// ---------------------------------------------------------------------------
__global__ __launch_bounds__(256) void node_proj_q(
    const float* __restrict__ nf,
    const float* __restrict__ Wq, const float* __restrict__ bq,
    float* __restrict__ Qn)
{
    __shared__ alignas(16) float xs[128][8];
    const int t = threadIdx.x;
    const int nb = blockIdx.x * 8;
    {
        const int node = t >> 5;
        const int k0 = (t & 31) * 4;
        const float4 x4 = *(const float4*)(nf + (size_t)(nb + node) * DN + k0);
        xs[k0 + 0][node] = x4.x;
        xs[k0 + 1][node] = x4.y;
        xs[k0 + 2][node] = x4.z;
        xs[k0 + 3][node] = x4.w;
    }
    __syncthreads();

    const int col = t & 127;
    const int grp = t >> 7;
    float aq[4];
    const float bqv = bq[col];
#pragma unroll
    for (int i = 0; i < 4; i++) aq[i] = bqv;

#pragma unroll 4
    for (int k = 0; k < 128; k++) {
        const float wq = Wq[k * DN + col];
        const float4 x = *(const float4*)&xs[k][grp * 4];
        aq[0] += x.x * wq; aq[1] += x.y * wq; aq[2] += x.z * wq; aq[3] += x.w * wq;
    }
#pragma unroll
    for (int i = 0; i < 4; i++)
        Qn[(size_t)(nb + grp * 4 + i) * DN + col] = aq[i];
}

// ---------------------------------------------------------------------------
// CSR build: histogram, 3-kernel exclusive scan, scatter -> epack{edge,src}.
// ---------------------------------------------------------------------------
__global__ __launch_bounds__(256) void edge_hist(
    const int* __restrict__ eidx, int* __restrict__ cnt)
{
    const int e = blockIdx.x * 256 + threadIdx.x;   // grid exact: NED/256
    atomicAdd(&cnt[eidx[NED + e]], 1);
}

#define SCAN_NB ((NND + 255) / 256)   // 196

__global__ __launch_bounds__(256) void scanA(
    const int* __restrict__ cnt, int* __restrict__ partial)
{
    const int idx = blockIdx.x * 256 + threadIdx.x;
    int v = (idx < NND) ? cnt[idx] : 0;
#pragma unroll
    for (int off = 1; off < 64; off <<= 1) v += __shfl_xor(v, off);
    __shared__ int wsum[4];
    if ((threadIdx.x & 63) == 0) wsum[threadIdx.x >> 6] = v;
    __syncthreads();
    if (threadIdx.x == 0)
        partial[blockIdx.x] = wsum[0] + wsum[1] + wsum[2] + wsum[3];
}

__global__ __launch_bounds__(256) void scanB(int* __restrict__ partial)
{
    __shared__ int s[256];
    const int t = threadIdx.x;
    const int v = (t < SCAN_NB) ? partial[t] : 0;
    s[t] = v;
    __syncthreads();
    for (int off = 1; off < 256; off <<= 1) {
        const int u = (t >= off) ? s[t - off] : 0;
        __syncthreads();
        s[t] += u;
        __syncthreads();
    }
    if (t < SCAN_NB) partial[t] = s[t] - v;   // exclusive
}

__global__ __launch_bounds__(256) void scanC(
    const int* __restrict__ cnt, const int* __restrict__ partial,
    int* __restrict__ offs)
{
    __shared__ int s[256];
    const int t = threadIdx.x;
    const int idx = blockIdx.x * 256 + t;
    const int v = (idx < NND) ? cnt[idx] : 0;
    s[t] = v;
    __syncthreads();
    for (int off = 1; off < 256; off <<= 1) {
        const int u = (t >= off) ? s[t - off] : 0;
        __syncthreads();
        s[t] += u;
        __syncthreads();
    }
    if (idx < NND) offs[idx] = partial[blockIdx.x] + s[t] - v;   // exclusive
}

// bumps offs in place: afterwards offs[n] == segment END (exclusive), beg = end-cnt[n]
__global__ __launch_bounds__(256) void edge_scatter(
    const int* __restrict__ eidx, int* __restrict__ offs, int2* __restrict__ epack)
{
    const int e = blockIdx.x * 256 + threadIdx.x;   // grid exact: NED/256
    const int pos = atomicAdd(&offs[eidx[NED + e]], 1);
    epack[pos] = make_int2(e, eidx[e]);
}

// ---------------------------------------------------------------------------
// K2 (fast tier): one wave per target node over its CSR segment.
//   logit[e,h] = 0.25*( q.Kn[src] + sum_k Qt[h,k]*ef[e,k] )
//     Qt[h,k] computed directly per lane (h=l>>3, j=l&7 owns k=j*8..j*8+7)
//   o = ( sum_e p*Vn[src] + G @ WvB ) / sum_e p,  G[h,k] = sum_e p[e,h]*ef[e,k]
// Software-pipelined: chunk t+1's epack+ef prefetched during chunk t; all 8
// Kn/Vn rows preloaded to registers before the compute loop (high MLP).
// ---------------------------------------------------------------------------
__global__ __launch_bounds__(256) void edge_aggregate(
    const float* __restrict__ ef,
    const int* __restrict__ cnt, const int* __restrict__ offs,
    const int2* __restrict__ epack,
    const float* __restrict__ Wk, const float* __restrict__ Wv,
    const float* __restrict__ Kn, const float* __restrict__ Vn,
    float* qo)
{
    __shared__ alignas(16) float efs[4][8][64];   // [wave][edge][k]
    const int t = threadIdx.x;
    const int w = t >> 6;
    const int l = t & 63;
    const int j = l & 7;
    const int es = l >> 3;                        // edge slot this lane stages
    const int node = blockIdx.x * 4 + w;          // grid exact: NND/4

    const int end = offs[node];                   // post-scatter: segment end
    const int beg = end - cnt[node];

    const float* __restrict__ WkB = Wk + 128 * DN;   // edge rows of Wk [192,128]
    const float* __restrict__ WvB = Wv + 128 * DN;

    const float2 q2 = *(const float2*)(qo + (size_t)node * DN + 2 * l);

    // ---- prologue: qh[m] = q[h*16+m] via bpermute from own head's lanes ----
    float qh[16];
#pragma unroll
    for (int m = 0; m < 8; m++) {
        qh[2 * m]     = __shfl(q2.x, (l & 56) + m);
        qh[2 * m + 1] = __shfl(q2.y, (l & 56) + m);
    }
    // qt[i] = Qt[h, j*8+i] = sum_m qh[m] * WkB[j*8+i][h*16+m]  (L1-resident W)
    float qt[8];
#pragma unroll
    for (int i = 0; i < 8; i++) {
        const float* wrow = WkB + (j * 8 + i) * DN + (l & 56) * 2;   // h*16
        const float4 w0 = *(const float4*)(wrow);
        const float4 w1 = *(const float4*)(wrow + 4);
        const float4 w2 = *(const float4*)(wrow + 8);
        const float4 w3 = *(const float4*)(wrow + 12);
        qt[i] = qh[0]  * w0.x + qh[1]  * w0.y + qh[2]  * w0.z + qh[3]  * w0.w
              + qh[4]  * w1.x + qh[5]  * w1.y + qh[6]  * w1.z + qh[7]  * w1.w
              + qh[8]  * w2.x + qh[9]  * w2.y + qh[10] * w2.z + qh[11] * w2.w
              + qh[12] * w3.x + qh[13] * w3.y + qh[14] * w3.z + qh[15] * w3.w;
    }

    float acc0 = 0.f, acc1 = 0.f, segacc = 0.f;
    float gt[8];
#pragma unroll
    for (int i = 0; i < 8; i++) gt[i] = 0.f;

    if (beg < end) {
        // prefetch chunk 0
        int2 ep = epack[min(beg + es, end - 1)];
        float4 A = *(const float4*)(ef + (size_t)ep.x * DE + j * 8);
        float4 B = *(const float4*)(ef + (size_t)ep.x * DE + j * 8 + 4);

        for (int base = beg; base < end; base += 8) {
            const int nbase = base + 8;
            int2 ep_n; float4 An, Bn;
            if (nbase < end) {                    // prefetch chunk t+1
                ep_n = epack[min(nbase + es, end - 1)];
                An = *(const float4*)(ef + (size_t)ep_n.x * DE + j * 8);
                Bn = *(const float4*)(ef + (size_t)ep_n.x * DE + j * 8 + 4);
            }
            // stage current chunk (wave-private, in-order LDS: no barrier)
            *(float4*)&efs[w][es][j * 8]     = A;
            *(float4*)&efs[w][es][j * 8 + 4] = B;

            // preload all 8 Kn/Vn rows (16 loads in flight)
            float2 kn[8], vn[8];
#pragma unroll
            for (int e = 0; e < 8; e++) {
                const int se = __builtin_amdgcn_readlane(ep.y, e * 8);
                kn[e] = *(const float2*)(Kn + (size_t)se * DN + 2 * l);
                vn[e] = *(const float2*)(Vn + (size_t)se * DN + 2 * l);
            }

#pragma unroll
            for (int e = 0; e < 8; e++) {
                const float4 efA = *(const float4*)&efs[w][e][j * 8];
                const float4 efB = *(const float4*)&efs[w][e][j * 8 + 4];
                float part = q2.x * kn[e].x + q2.y * kn[e].y
                           + efA.x * qt[0] + efA.y * qt[1] + efA.z * qt[2] + efA.w * qt[3]
                           + efB.x * qt[4] + efB.y * qt[5] + efB.z * qt[6] + efB.w * qt[7];
                part += __shfl_xor(part, 1);
                part += __shfl_xor(part, 2);
                part += __shfl_xor(part, 4);      // logit[e,h] on 8-lane head group
                const float arg = fminf(fmaxf(part * 0.25f, -60.f), 60.f);  // 1/sqrt(16)
                const float p = (base + e < end) ? __expf(arg) : 0.f;       // mask pads
                acc0 += p * vn[e].x;
                acc1 += p * vn[e].y;
                segacc += p;
                gt[0] += p * efA.x; gt[1] += p * efA.y; gt[2] += p * efA.z; gt[3] += p * efA.w;
                gt[4] += p * efB.x; gt[5] += p * efB.y; gt[6] += p * efB.z; gt[7] += p * efB.w;
            }
            ep = ep_n; A = An; B = Bn;
        }
    }

    // ---- epilogue: o_edge = G @ WvB (G slices broadcast via bpermute) ----
    float oe0 = 0.f, oe1 = 0.f;
#pragma unroll 16
    for (int k = 0; k < 64; k++) {
        const float g = __shfl(gt[k & 7], (l & 56) | (k >> 3));
        const float2 wv2 = *(const float2*)(WvB + k * DN + 2 * l);
        oe0 += g * wv2.x;
        oe1 += g * wv2.y;
    }
    acc0 += oe0;
    acc1 += oe1;

    const float r = (segacc > 0.f) ? 1.f / segacc : 0.f;   // deg==0 -> zeros
    float* orow = qo + (size_t)node * DN + 2 * l;
    orow[0] = sane(acc0 * r);
    orow[1] = sane(acc1 * r);
}

// ---------------------------------------------------------------------------
// K2b (fallback tier, needs only 27.2MB ws): recompute full K/V per edge,
// scatter with atomics. (unchanged)
// ---------------------------------------------------------------------------
__global__ __launch_bounds__(256) void edge_pass_full(
    const float* __restrict__ nf, const float* __restrict__ ef,
    const int* __restrict__ eidx,
    const float* __restrict__ Wk, const float* __restrict__ bk,
    const float* __restrict__ Wv, const float* __restrict__ bv,
    const float* __restrict__ Qn,
    float* __restrict__ o_un, float* __restrict__ seg)
{
    __shared__ alignas(16) float kvs[4][192][4];
    const int t = threadIdx.x;
    const int w = t >> 6;
    const int l = t & 63;
    const int eb = blockIdx.x * 16 + w * 4;

    int src[4], tgt[4];
#pragma unroll
    for (int e = 0; e < 4; e++) {
        src[e] = eidx[eb + e];
        tgt[e] = eidx[NED + eb + e];
    }

#pragma unroll
    for (int it = 0; it < 3; it++) {
        const int idx = it * 64 + l;
        const int e = idx / 48;
        const int pos = (idx % 48) * 4;
        const float* p = (pos < 128)
            ? nf + (size_t)src[e] * DN + pos
            : ef + (size_t)(eb + e) * DE + (pos - 128);
        const float4 x4 = *(const float4*)p;
        kvs[w][pos + 0][e] = x4.x;
        kvs[w][pos + 1][e] = x4.y;
        kvs[w][pos + 2][e] = x4.z;
        kvs[w][pos + 3][e] = x4.w;
    }
    __syncthreads();

    const float bk0 = bk[2 * l], bk1 = bk[2 * l + 1];
    const float bv0 = bv[2 * l], bv1 = bv[2 * l + 1];
    float accK[4][2] = {{bk0,bk1},{bk0,bk1},{bk0,bk1},{bk0,bk1}};
    float accV[4][2] = {{bv0,bv1},{bv0,bv1},{bv0,bv1},{bv0,bv1}};

#pragma unroll 4
    for (int k = 0; k < DKV; k++) {
        const float4 e4 = *(const float4*)&kvs[w][k][0];
        const float2 wk2 = *(const float2*)(Wk + k * DN + 2 * l);
        const float2 wv2 = *(const float2*)(Wv + k * DN + 2 * l);
        accK[0][0] += e4.x * wk2.x; accK[0][1] += e4.x * wk2.y;
        accK[1][0] += e4.y * wk2.x; accK[1][1] += e4.y * wk2.y;
        accK[2][0] += e4.z * wk2.x; accK[2][1] += e4.z * wk2.y;
        accK[3][0] += e4.w * wk2.x; accK[3][1] += e4.w * wk2.y;
        accV[0][0] += e4.x * wv2.x; accV[0][1] += e4.x * wv2.y;
        accV[1][0] += e4.y * wv2.x; accV[1][1] += e4.y * wv2.y;
        accV[2][0] += e4.z * wv2.x; accV[2][1] += e4.z * wv2.y;
        accV[3][0] += e4.w * wv2.x; accV[3][1] += e4.w * wv2.y;
    }

    const int h = l >> 3;
#pragma unroll
    for (int e = 0; e < 4; e++) {
        const float2 q2 = *(const float2*)(Qn + (size_t)tgt[e] * DN + 2 * l);
        float part = q2.x * accK[e][0] + q2.y * accK[e][1];
        part += __shfl_xor(part, 1);
        part += __shfl_xor(part, 2);
        part += __shfl_xor(part, 4);
        float arg = fminf(fmaxf(part * 0.25f, -60.f), 60.f);
        const float p = __expf(arg);

        atomicAdd(&o_un[(size_t)tgt[e] * DN + 2 * l],     p * accV[e][0]);
        atomicAdd(&o_un[(size_t)tgt[e] * DN + 2 * l + 1], p * accV[e][1]);
        if ((l & 7) == 0) atomicAdd(&seg[tgt[e] * NH + h], p);
    }
}

// ---------------------------------------------------------------------------
// K3: out = sanitize(o / seg) @ Wo + bo. seg == nullptr -> o already
// normalized (fast tier; o aliases out, block reads its 8 rows before the
// barrier and writes only those rows after it).
// ---------------------------------------------------------------------------
__global__ __launch_bounds__(256) void out_proj(
    const float* o_un, const float* __restrict__ seg,
    const float* __restrict__ Wo, const float* __restrict__ bo,
    float* out)
{
    __shared__ alignas(16) float xs[128][8];
    const int t = threadIdx.x;
    const int nb = blockIdx.x * 8;
    {
        const int node = t >> 5;
        const int k0 = (t & 31) * 4;
        const float4 v = *(const float4*)(o_un + (size_t)(nb + node) * DN + k0);
        float r = 1.f;
        if (seg) {
            const float s = seg[(nb + node) * NH + (k0 >> 4)];
            r = (s > 0.f) ? 1.f / s : 0.f;
        }
        xs[k0 + 0][node] = sane(v.x * r);
        xs[k0 + 1][node] = sane(v.y * r);
        xs[k0 + 2][node] = sane(v.z * r);
        xs[k0 + 3][node] = sane(v.w * r);
    }
    __syncthreads();

    const int col = t & 127;
    const int grp = t >> 7;
    float acc[4];
    const float b = bo[col];
#pragma unroll
    for (int i = 0; i < 4; i++) acc[i] = b;

#pragma unroll 4
    for (int k = 0; k < 128; k++) {
        const float wo = Wo[k * DN + col];
        const float4 x = *(const float4*)&xs[k][grp * 4];
        acc[0] += x.x * wo; acc[1] += x.y * wo; acc[2] += x.z * wo; acc[3] += x.w * wo;
    }
#pragma unroll
    for (int i = 0; i < 4; i++)
        out[(size_t)(nb + grp * 4 + i) * DN + col] = acc[i];
}

// ---------------------------------------------------------------------------
extern "C" void kernel_launch(void* const* d_in, const int* in_sizes, int n_in,
                              void* d_out, int out_size, void* d_ws, size_t ws_size,
                              hipStream_t stream) {
    const float* nf   = (const float*)d_in[0];
    const float* ef   = (const float*)d_in[1];
    const int*   eidx = (const int*)d_in[2];
    const float* Wq   = (const float*)d_in[3];
    const float* bq   = (const float*)d_in[4];
    const float* Wk   = (const float*)d_in[5];
    const float* bk   = (const float*)d_in[6];
    const float* Wv   = (const float*)d_in[7];
    const float* bv   = (const float*)d_in[8];
    const float* Wo   = (const float*)d_in[9];
    const float* bo   = (const float*)d_in[10];
    float* out = (float*)d_out;

    // Qn lives in d_out; edge_aggregate overwrites it in place with normalized o,
    // out_proj then overwrites with the final output.
    float* Qn = out;

    const size_t tabBytes = (size_t)NND * DN * sizeof(float);                  // 25.6 MB
    const size_t csrBytes = 2 * tabBytes
                          + ((size_t)2 * NND + 2 * NED + SCAN_NB) * sizeof(int); // ~58 MB
    const size_t accBytes = tabBytes + (size_t)NND * NH * sizeof(float);       // 27.2 MB

    if (ws_size >= csrBytes) {
        float* Kn     = (float*)d_ws;
        float* Vn     = Kn + (size_t)NND * DN;
        int*   cnt    = (int*)(Vn + (size_t)NND * DN);
        int*   offs   = cnt + NND;
        int2*  epack  = (int2*)(offs + NND);        // 8B-aligned (offset 51.6e6 B)
        int*   partial= (int*)(epack + NED);
        hipMemsetAsync(cnt, 0, NND * sizeof(int), stream);
        node_proj_qkv<<<NND / 8, 256, 0, stream>>>(nf, Wq, bq, Wk, bk, Wv, bv, Qn, Kn, Vn);
        edge_hist<<<NED / 256, 256, 0, stream>>>(eidx, cnt);
        scanA<<<SCAN_NB, 256, 0, stream>>>(cnt, partial);
        scanB<<<1, 256, 0, stream>>>(partial);
        scanC<<<SCAN_NB, 256, 0, stream>>>(cnt, partial, offs);
        edge_scatter<<<NED / 256, 256, 0, stream>>>(eidx, offs, epack);
        edge_aggregate<<<NND / 4, 256, 0, stream>>>(ef, cnt, offs, epack,
                                                    Wk, Wv, Kn, Vn, Qn);
        out_proj<<<NND / 8, 256, 0, stream>>>(Qn, nullptr, Wo, bo, out);
    } else {
        float* o_un = (float*)d_ws;
        float* seg  = o_un + (size_t)NND * DN;
        hipMemsetAsync(o_un, 0, accBytes, stream);
        node_proj_q<<<NND / 8, 256, 0, stream>>>(nf, Wq, bq, Qn);
        edge_pass_full<<<NED / 16, 256, 0, stream>>>(nf, ef, eidx, Wk, bk, Wv, bv, Qn, o_un, seg);
        out_proj<<<NND / 8, 256, 0, stream>>>(o_un, seg, Wo, bo, out);
    }
}

// Round 7
// 789.704 us; speedup vs baseline: 1.7213x; 1.0965x over previous
//
#include <hip/hip_runtime.h>

#define NND 50000
#define NED 800000
#define DN 128
#define DE 64
#define DKV 192
#define NH 8
#define HD 16

typedef float f32x4 __attribute__((ext_vector_type(4)));
typedef int   i32x2 __attribute__((ext_vector_type(2)));

__device__ __forceinline__ float sane(float x) {
    return (x == x && fabsf(x) < 1e30f) ? x : 0.f;
}

// nontemporal float4 load (builtin requires clang vector types, not HIP classes)
__device__ __forceinline__ float4 nt_load4(const float* p) {
    f32x4 v = __builtin_nontemporal_load((const f32x4*)p);
    return make_float4(v.x, v.y, v.z, v.w);
}
__device__ __forceinline__ int2 nt_load2i(const int2* p) {
    i32x2 v = __builtin_nontemporal_load((const i32x2*)p);
    return make_int2(v.x, v.y);
}

// ---------------------------------------------------------------------------
// K1a (fast tier): Qn = X@Wq+bq -> d_out (fp32), Kn/Vn = X@W*[:128]+b* -> ws.
// 16 nodes/block; xs[16][128] (contiguous staging writes, wave-uniform
// broadcast reads). Each weight load amortized over 8 nodes.
// ---------------------------------------------------------------------------
__global__ __launch_bounds__(256) void node_proj_qkv(
    const float* __restrict__ nf,
    const float* __restrict__ Wq, const float* __restrict__ bq,
    const float* __restrict__ Wk, const float* __restrict__ bk,
    const float* __restrict__ Wv, const float* __restrict__ bv,
    float* __restrict__ Qn, float* __restrict__ Kn, float* __restrict__ Vn)
{
    __shared__ alignas(16) float xs[16][128];
    const int t = threadIdx.x;
    const int nb = blockIdx.x * 16;
#pragma unroll
    for (int s = 0; s < 2; s++) {
        const int idx = s * 256 + t;
        const int node = idx >> 5;          // 0..15
        const int k0 = (idx & 31) * 4;      // 0..124
        const float4 x4 = nt_load4(nf + (size_t)(nb + node) * DN + k0);
        *(float4*)&xs[node][k0] = x4;
    }
    __syncthreads();

    const int col = t & 127;
    const int g8 = (t >> 7) * 8;            // 0 or 8: this thread's 8 nodes
    float aq[8], ak[8], av[8];
    const float bqv = bq[col], bkv = bk[col], bvv = bv[col];
#pragma unroll
    for (int n = 0; n < 8; n++) { aq[n] = bqv; ak[n] = bkv; av[n] = bvv; }

#pragma unroll 2
    for (int kk = 0; kk < 128; kk += 4) {
        float4 xv[8];
#pragma unroll
        for (int n = 0; n < 8; n++) xv[n] = *(const float4*)&xs[g8 + n][kk];

        const float wq0 = Wq[(kk + 0) * DN + col];
        const float wq1 = Wq[(kk + 1) * DN + col];
        const float wq2 = Wq[(kk + 2) * DN + col];
        const float wq3 = Wq[(kk + 3) * DN + col];
        const float wk0 = Wk[(kk + 0) * DN + col];
        const float wk1 = Wk[(kk + 1) * DN + col];
        const float wk2 = Wk[(kk + 2) * DN + col];
        const float wk3 = Wk[(kk + 3) * DN + col];
        const float wv0 = Wv[(kk + 0) * DN + col];
        const float wv1 = Wv[(kk + 1) * DN + col];
        const float wv2 = Wv[(kk + 2) * DN + col];
        const float wv3 = Wv[(kk + 3) * DN + col];
#pragma unroll
        for (int n = 0; n < 8; n++) {
            aq[n] += xv[n].x * wq0 + xv[n].y * wq1 + xv[n].z * wq2 + xv[n].w * wq3;
            ak[n] += xv[n].x * wk0 + xv[n].y * wk1 + xv[n].z * wk2 + xv[n].w * wk3;
            av[n] += xv[n].x * wv0 + xv[n].y * wv1 + xv[n].z * wv2 + xv[n].w * wv3;
        }
    }
#pragma unroll
    for (int n = 0; n < 8; n++) {
        const size_t r = (size_t)(nb + g8 + n) * DN + col;
        Qn[r] = aq[n]; Kn[r] = ak[n]; Vn[r] = av[n];
    }
}

// ---------------------------------------------------------------------------
// K1b (fallback tier): only Qn -> d_out (fp32)
// ---------------------------------------------------------------------------
__global__ __launch_bounds__(256) void node_proj_q(
    const float* __restrict__ nf,
    const float* __restrict__ Wq, const float* __restrict__ bq,
    float* __restrict__ Qn)
{
    __shared__ alignas(16) float xs[128][8];
    const int t = threadIdx.x;
    const int nb = blockIdx.x * 8;
    {
        const int node = t >> 5;
        const int k0 = (t & 31) * 4;
        const float4 x4 = *(const float4*)(nf + (size_t)(nb + node) * DN + k0);
        xs[k0 + 0][node] = x4.x;
        xs[k0 + 1][node] = x4.y;
        xs[k0 + 2][node] = x4.z;
        xs[k0 + 3][node] = x4.w;
    }
    __syncthreads();

    const int col = t & 127;
    const int grp = t >> 7;
    float aq[4];
    const float bqv = bq[col];
#pragma unroll
    for (int i = 0; i < 4; i++) aq[i] = bqv;

#pragma unroll 4
    for (int k = 0; k < 128; k++) {
        const float wq = Wq[k * DN + col];
        const float4 x = *(const float4*)&xs[k][grp * 4];
        aq[0] += x.x * wq; aq[1] += x.y * wq; aq[2] += x.z * wq; aq[3] += x.w * wq;
    }
#pragma unroll
    for (int i = 0; i < 4; i++)
        Qn[(size_t)(nb + grp * 4 + i) * DN + col] = aq[i];
}

// ---------------------------------------------------------------------------
// CSR build: histogram, 3-kernel exclusive scan, scatter -> epack{edge,src}.
// ---------------------------------------------------------------------------
__global__ __launch_bounds__(256) void edge_hist(
    const int* __restrict__ eidx, int* __restrict__ cnt)
{
    const int e = blockIdx.x * 256 + threadIdx.x;   // grid exact: NED/256
    atomicAdd(&cnt[eidx[NED + e]], 1);
}

#define SCAN_NB ((NND + 255) / 256)   // 196

__global__ __launch_bounds__(256) void scanA(
    const int* __restrict__ cnt, int* __restrict__ partial)
{
    const int idx = blockIdx.x * 256 + threadIdx.x;
    int v = (idx < NND) ? cnt[idx] : 0;
#pragma unroll
    for (int off = 1; off < 64; off <<= 1) v += __shfl_xor(v, off);
    __shared__ int wsum[4];
    if ((threadIdx.x & 63) == 0) wsum[threadIdx.x >> 6] = v;
    __syncthreads();
    if (threadIdx.x == 0)
        partial[blockIdx.x] = wsum[0] + wsum[1] + wsum[2] + wsum[3];
}

__global__ __launch_bounds__(256) void scanB(int* __restrict__ partial)
{
    __shared__ int s[256];
    const int t = threadIdx.x;
    const int v = (t < SCAN_NB) ? partial[t] : 0;
    s[t] = v;
    __syncthreads();
    for (int off = 1; off < 256; off <<= 1) {
        const int u = (t >= off) ? s[t - off] : 0;
        __syncthreads();
        s[t] += u;
        __syncthreads();
    }
    if (t < SCAN_NB) partial[t] = s[t] - v;   // exclusive
}

__global__ __launch_bounds__(256) void scanC(
    const int* __restrict__ cnt, const int* __restrict__ partial,
    int* __restrict__ offs)
{
    __shared__ int s[256];
    const int t = threadIdx.x;
    const int idx = blockIdx.x * 256 + t;
    const int v = (idx < NND) ? cnt[idx] : 0;
    s[t] = v;
    __syncthreads();
    for (int off = 1; off < 256; off <<= 1) {
        const int u = (t >= off) ? s[t - off] : 0;
        __syncthreads();
        s[t] += u;
        __syncthreads();
    }
    if (idx < NND) offs[idx] = partial[blockIdx.x] + s[t] - v;   // exclusive
}

// bumps offs in place: afterwards offs[n] == segment END (exclusive), beg = end-cnt[n]
__global__ __launch_bounds__(256) void edge_scatter(
    const int* __restrict__ eidx, int* __restrict__ offs, int2* __restrict__ epack)
{
    const int e = blockIdx.x * 256 + threadIdx.x;   // grid exact: NED/256
    const int pos = atomicAdd(&offs[eidx[NED + e]], 1);
    epack[pos] = make_int2(e, eidx[e]);
}

// ---------------------------------------------------------------------------
// K2 (fast tier): one wave per target node over its CSR segment.
// R3-proven structure (no manual pipelining — compiler schedules the gathers).
//   logit[e,h] = 0.25*( q.Kn[src] + sum_k Qt[h,k]*ef[e,k] )
//   o = ( sum_e p*Vn[src] + G @ WvB ) / sum_e p,  G[h,k] = sum_e p[e,h]*ef[e,k]
// ef/epack are touched exactly once -> nontemporal loads keep Kn/Vn in LLC.
// ---------------------------------------------------------------------------
__global__ __launch_bounds__(256) void edge_aggregate(
    const float* __restrict__ ef,
    const int* __restrict__ cnt, const int* __restrict__ offs,
    const int2* __restrict__ epack,
    const float* __restrict__ Wk, const float* __restrict__ Wv,
    const float* __restrict__ Kn, const float* __restrict__ Vn,
    float* qo)
{
    __shared__ alignas(16) float efs[4][8][64];   // [wave][edge][k]
    const int t = threadIdx.x;
    const int w = t >> 6;
    const int l = t & 63;
    const int j = l & 7;
    const int node = blockIdx.x * 4 + w;          // grid exact: NND/4

    const int end = offs[node];                   // post-scatter: segment end
    const int beg = end - cnt[node];

    const float* __restrict__ WkB = Wk + 128 * DN;   // edge rows of Wk [192,128]
    const float* __restrict__ WvB = Wv + 128 * DN;

    const float2 q2 = *(const float2*)(qo + (size_t)node * DN + 2 * l);

    // ---- prologue: Qt[h, j*8+i] into qt[i] (coalesced WkB row reads) ----
    float qt[8];
#pragma unroll
    for (int i = 0; i < 8; i++) qt[i] = 0.f;
#pragma unroll 16
    for (int k = 0; k < 64; k++) {
        const float2 wk2 = *(const float2*)(WkB + k * DN + 2 * l);
        float part = q2.x * wk2.x + q2.y * wk2.y;
        part += __shfl_xor(part, 1);
        part += __shfl_xor(part, 2);
        part += __shfl_xor(part, 4);              // sum over head's 16 cols
        if (j == (k >> 3)) qt[k & 7] = part;
    }

    float acc0 = 0.f, acc1 = 0.f, segacc = 0.f;
    float gt[8];
#pragma unroll
    for (int i = 0; i < 8; i++) gt[i] = 0.f;

    for (int base = beg; base < end; base += 8) {
        const int myE = min(base + (l >> 3), end - 1);   // clamp padded slots
        const int2 ep = nt_load2i(&epack[myE]);
        // stage ef chunk: lane stages its edge's k-slice j*8..j*8+7
        const float4 A = nt_load4(ef + (size_t)ep.x * DE + j * 8);
        const float4 B = nt_load4(ef + (size_t)ep.x * DE + j * 8 + 4);
        *(float4*)&efs[w][l >> 3][j * 8]     = A;
        *(float4*)&efs[w][l >> 3][j * 8 + 4] = B;

#pragma unroll
        for (int e = 0; e < 8; e++) {
            const int se = __builtin_amdgcn_readlane(ep.y, e * 8);
            const float4 efA = *(const float4*)&efs[w][e][j * 8];
            const float4 efB = *(const float4*)&efs[w][e][j * 8 + 4];
            const float2 kn2 = *(const float2*)(Kn + (size_t)se * DN + 2 * l);
            float part = q2.x * kn2.x + q2.y * kn2.y
                       + efA.x * qt[0] + efA.y * qt[1] + efA.z * qt[2] + efA.w * qt[3]
                       + efB.x * qt[4] + efB.y * qt[5] + efB.z * qt[6] + efB.w * qt[7];
            part += __shfl_xor(part, 1);
            part += __shfl_xor(part, 2);
            part += __shfl_xor(part, 4);          // logit[e,h] on 8-lane head group
            const float arg = fminf(fmaxf(part * 0.25f, -60.f), 60.f);  // 1/sqrt(16)
            const float p = (base + e < end) ? __expf(arg) : 0.f;       // mask pads
            const float2 vn2 = *(const float2*)(Vn + (size_t)se * DN + 2 * l);
            acc0 += p * vn2.x;
            acc1 += p * vn2.y;
            segacc += p;
            gt[0] += p * efA.x; gt[1] += p * efA.y; gt[2] += p * efA.z; gt[3] += p * efA.w;
            gt[4] += p * efB.x; gt[5] += p * efB.y; gt[6] += p * efB.z; gt[7] += p * efB.w;
        }
    }

    // ---- epilogue: o_edge = G @ WvB (G slices broadcast via shfl) ----
    float oe0 = 0.f, oe1 = 0.f;
#pragma unroll 16
    for (int k = 0; k < 64; k++) {
        const float g = __shfl(gt[k & 7], (l & 56) | (k >> 3));
        const float2 wv2 = *(const float2*)(WvB + k * DN + 2 * l);
        oe0 += g * wv2.x;
        oe1 += g * wv2.y;
    }
    acc0 += oe0;
    acc1 += oe1;

    const float r = (segacc > 0.f) ? 1.f / segacc : 0.f;   // deg==0 -> zeros
    float* orow = qo + (size_t)node * DN + 2 * l;
    orow[0] = sane(acc0 * r);
    orow[1] = sane(acc1 * r);
}

// ---------------------------------------------------------------------------
// K2b (fallback tier, needs only 27.2MB ws): recompute full K/V per edge,
// scatter with atomics. (unchanged)
// ---------------------------------------------------------------------------
__global__ __launch_bounds__(256) void edge_pass_full(
    const float* __restrict__ nf, const float* __restrict__ ef,
    const int* __restrict__ eidx,
    const float* __restrict__ Wk, const float* __restrict__ bk,
    const float* __restrict__ Wv, const float* __restrict__ bv,
    const float* __restrict__ Qn,
    float* __restrict__ o_un, float* __restrict__ seg)
{
    __shared__ alignas(16) float kvs[4][192][4];
    const int t = threadIdx.x;
    const int w = t >> 6;
    const int l = t & 63;
    const int eb = blockIdx.x * 16 + w * 4;

    int src[4], tgt[4];
#pragma unroll
    for (int e = 0; e < 4; e++) {
        src[e] = eidx[eb + e];
        tgt[e] = eidx[NED + eb + e];
    }

#pragma unroll
    for (int it = 0; it < 3; it++) {
        const int idx = it * 64 + l;
        const int e = idx / 48;
        const int pos = (idx % 48) * 4;
        const float* p = (pos < 128)
            ? nf + (size_t)src[e] * DN + pos
            : ef + (size_t)(eb + e) * DE + (pos - 128);
        const float4 x4 = *(const float4*)p;
        kvs[w][pos + 0][e] = x4.x;
        kvs[w][pos + 1][e] = x4.y;
        kvs[w][pos + 2][e] = x4.z;
        kvs[w][pos + 3][e] = x4.w;
    }
    __syncthreads();

    const float bk0 = bk[2 * l], bk1 = bk[2 * l + 1];
    const float bv0 = bv[2 * l], bv1 = bv[2 * l + 1];
    float accK[4][2] = {{bk0,bk1},{bk0,bk1},{bk0,bk1},{bk0,bk1}};
    float accV[4][2] = {{bv0,bv1},{bv0,bv1},{bv0,bv1},{bv0,bv1}};

#pragma unroll 4
    for (int k = 0; k < DKV; k++) {
        const float4 e4 = *(const float4*)&kvs[w][k][0];
        const float2 wk2 = *(const float2*)(Wk + k * DN + 2 * l);
        const float2 wv2 = *(const float2*)(Wv + k * DN + 2 * l);
        accK[0][0] += e4.x * wk2.x; accK[0][1] += e4.x * wk2.y;
        accK[1][0] += e4.y * wk2.x; accK[1][1] += e4.y * wk2.y;
        accK[2][0] += e4.z * wk2.x; accK[2][1] += e4.z * wk2.y;
        accK[3][0] += e4.w * wk2.x; accK[3][1] += e4.w * wk2.y;
        accV[0][0] += e4.x * wv2.x; accV[0][1] += e4.x * wv2.y;
        accV[1][0] += e4.y * wv2.x; accV[1][1] += e4.y * wv2.y;
        accV[2][0] += e4.z * wv2.x; accV[2][1] += e4.z * wv2.y;
        accV[3][0] += e4.w * wv2.x; accV[3][1] += e4.w * wv2.y;
    }

    const int h = l >> 3;
#pragma unroll
    for (int e = 0; e < 4; e++) {
        const float2 q2 = *(const float2*)(Qn + (size_t)tgt[e] * DN + 2 * l);
        float part = q2.x * accK[e][0] + q2.y * accK[e][1];
        part += __shfl_xor(part, 1);
        part += __shfl_xor(part, 2);
        part += __shfl_xor(part, 4);
        float arg = fminf(fmaxf(part * 0.25f, -60.f), 60.f);
        const float p = __expf(arg);

        atomicAdd(&o_un[(size_t)tgt[e] * DN + 2 * l],     p * accV[e][0]);
        atomicAdd(&o_un[(size_t)tgt[e] * DN + 2 * l + 1], p * accV[e][1]);
        if ((l & 7) == 0) atomicAdd(&seg[tgt[e] * NH + h], p);
    }
}

// ---------------------------------------------------------------------------
// K3: out = sanitize(o / seg) @ Wo + bo. seg == nullptr -> o already
// normalized. 16 nodes/block; xs[16][128]; weight load amortized over 8 nodes.
// Fast tier: o aliases out; block reads its 16 rows before the barrier and
// writes only those rows after it.
// ---------------------------------------------------------------------------
__global__ __launch_bounds__(256) void out_proj(
    const float* o_un, const float* __restrict__ seg,
    const float* __restrict__ Wo, const float* __restrict__ bo,
    float* out)
{
    __shared__ alignas(16) float xs[16][128];
    const int t = threadIdx.x;
    const int nb = blockIdx.x * 16;
#pragma unroll
    for (int s = 0; s < 2; s++) {
        const int idx = s * 256 + t;
        const int node = idx >> 5;          // 0..15
        const int k0 = (idx & 31) * 4;      // same head for all 4 elems
        const float4 v = *(const float4*)(o_un + (size_t)(nb + node) * DN + k0);
        float r = 1.f;
        if (seg) {
            const float sv = seg[(nb + node) * NH + (k0 >> 4)];
            r = (sv > 0.f) ? 1.f / sv : 0.f;
        }
        float4 o4;
        o4.x = sane(v.x * r);
        o4.y = sane(v.y * r);
        o4.z = sane(v.z * r);
        o4.w = sane(v.w * r);
        *(float4*)&xs[node][k0] = o4;
    }
    __syncthreads();

    const int col = t & 127;
    const int g8 = (t >> 7) * 8;
    float acc[8];
    const float b = bo[col];
#pragma unroll
    for (int n = 0; n < 8; n++) acc[n] = b;

#pragma unroll 2
    for (int kk = 0; kk < 128; kk += 4) {
        float4 xv[8];
#pragma unroll
        for (int n = 0; n < 8; n++) xv[n] = *(const float4*)&xs[g8 + n][kk];
        const float w0 = Wo[(kk + 0) * DN + col];
        const float w1 = Wo[(kk + 1) * DN + col];
        const float w2 = Wo[(kk + 2) * DN + col];
        const float w3 = Wo[(kk + 3) * DN + col];
#pragma unroll
        for (int n = 0; n < 8; n++)
            acc[n] += xv[n].x * w0 + xv[n].y * w1 + xv[n].z * w2 + xv[n].w * w3;
    }
#pragma unroll
    for (int n = 0; n < 8; n++)
        out[(size_t)(nb + g8 + n) * DN + col] = acc[n];
}

// ---------------------------------------------------------------------------
extern "C" void kernel_launch(void* const* d_in, const int* in_sizes, int n_in,
                              void* d_out, int out_size, void* d_ws, size_t ws_size,
                              hipStream_t stream) {
    const float* nf   = (const float*)d_in[0];
    const float* ef   = (const float*)d_in[1];
    const int*   eidx = (const int*)d_in[2];
    const float* Wq   = (const float*)d_in[3];
    const float* bq   = (const float*)d_in[4];
    const float* Wk   = (const float*)d_in[5];
    const float* bk   = (const float*)d_in[6];
    const float* Wv   = (const float*)d_in[7];
    const float* bv   = (const float*)d_in[8];
    const float* Wo   = (const float*)d_in[9];
    const float* bo   = (const float*)d_in[10];
    float* out = (float*)d_out;

    // Qn lives in d_out; edge_aggregate overwrites it in place with normalized o,
    // out_proj then overwrites with the final output.
    float* Qn = out;

    const size_t tabBytes = (size_t)NND * DN * sizeof(float);                  // 25.6 MB
    const size_t csrBytes = 2 * tabBytes
                          + ((size_t)2 * NND + 2 * NED + SCAN_NB) * sizeof(int); // ~58 MB
    const size_t accBytes = tabBytes + (size_t)NND * NH * sizeof(float);       // 27.2 MB

    if (ws_size >= csrBytes) {
        float* Kn     = (float*)d_ws;
        float* Vn     = Kn + (size_t)NND * DN;
        int*   cnt    = (int*)(Vn + (size_t)NND * DN);
        int*   offs   = cnt + NND;
        int2*  epack  = (int2*)(offs + NND);        // 8B-aligned
        int*   partial= (int*)(epack + NED);
        (void)hipMemsetAsync(cnt, 0, NND * sizeof(int), stream);
        node_proj_qkv<<<NND / 16, 256, 0, stream>>>(nf, Wq, bq, Wk, bk, Wv, bv, Qn, Kn, Vn);
        edge_hist<<<NED / 256, 256, 0, stream>>>(eidx, cnt);
        scanA<<<SCAN_NB, 256, 0, stream>>>(cnt, partial);
        scanB<<<1, 256, 0, stream>>>(partial);
        scanC<<<SCAN_NB, 256, 0, stream>>>(cnt, partial, offs);
        edge_scatter<<<NED / 256, 256, 0, stream>>>(eidx, offs, epack);
        edge_aggregate<<<NND / 4, 256, 0, stream>>>(ef, cnt, offs, epack,
                                                    Wk, Wv, Kn, Vn, Qn);
        out_proj<<<NND / 16, 256, 0, stream>>>(Qn, nullptr, Wo, bo, out);
    } else {
        float* o_un = (float*)d_ws;
        float* seg  = o_un + (size_t)NND * DN;
        (void)hipMemsetAsync(o_un, 0, accBytes, stream);
        node_proj_q<<<NND / 8, 256, 0, stream>>>(nf, Wq, bq, Qn);
        edge_pass_full<<<NED / 16, 256, 0, stream>>>(nf, ef, eidx, Wk, bk, Wv, bv, Qn, o_un, seg);
        out_proj<<<NND / 16, 256, 0, stream>>>(o_un, seg, Wo, bo, out);
    }
}

// Round 8
// 725.824 us; speedup vs baseline: 1.8728x; 1.0880x over previous
//
#include <hip/hip_runtime.h>

#define NND 50000
#define NED 800000
#define DN 128
#define DE 64
#define DKV 192
#define NH 8
#define HD 16

typedef float f32x4 __attribute__((ext_vector_type(4)));
typedef int   i32x2 __attribute__((ext_vector_type(2)));

__device__ __forceinline__ float sane(float x) {
    return (x == x && fabsf(x) < 1e30f) ? x : 0.f;
}

// nontemporal float4 load (builtin requires clang vector types, not HIP classes)
__device__ __forceinline__ float4 nt_load4(const float* p) {
    f32x4 v = __builtin_nontemporal_load((const f32x4*)p);
    return make_float4(v.x, v.y, v.z, v.w);
}
__device__ __forceinline__ int2 nt_load2i(const int2* p) {
    i32x2 v = __builtin_nontemporal_load((const i32x2*)p);
    return make_int2(v.x, v.y);
}

// ---------------------------------------------------------------------------
// K1a (fast tier): Qn = X@Wq+bq -> d_out, Kn/Vn -> ws. 16 nodes/block.
// Optional phase 2 (Qt != nullptr): Qt[n][h*64+k] = sum_m q[n][h*16+m]*WkB[k][h*16+m]
// (the per-node K-side projection of q, hoisted out of edge_aggregate).
// ---------------------------------------------------------------------------
__global__ __launch_bounds__(256) void node_proj_qkv(
    const float* __restrict__ nf,
    const float* __restrict__ Wq, const float* __restrict__ bq,
    const float* __restrict__ Wk, const float* __restrict__ bk,
    const float* __restrict__ Wv, const float* __restrict__ bv,
    float* __restrict__ Qn, float* __restrict__ Kn, float* __restrict__ Vn,
    float* __restrict__ Qt)
{
    __shared__ alignas(16) float xs[16][128];
    const int t = threadIdx.x;
    const int nb = blockIdx.x * 16;
#pragma unroll
    for (int s = 0; s < 2; s++) {
        const int idx = s * 256 + t;
        const int node = idx >> 5;          // 0..15
        const int k0 = (idx & 31) * 4;      // 0..124
        const float4 x4 = nt_load4(nf + (size_t)(nb + node) * DN + k0);
        *(float4*)&xs[node][k0] = x4;
    }
    __syncthreads();

    const int col = t & 127;
    const int g8 = (t >> 7) * 8;            // 0 or 8: this thread's 8 nodes
    float aq[8], ak[8], av[8];
    const float bqv = bq[col], bkv = bk[col], bvv = bv[col];
#pragma unroll
    for (int n = 0; n < 8; n++) { aq[n] = bqv; ak[n] = bkv; av[n] = bvv; }

#pragma unroll 2
    for (int kk = 0; kk < 128; kk += 4) {
        float4 xv[8];
#pragma unroll
        for (int n = 0; n < 8; n++) xv[n] = *(const float4*)&xs[g8 + n][kk];

        const float wq0 = Wq[(kk + 0) * DN + col];
        const float wq1 = Wq[(kk + 1) * DN + col];
        const float wq2 = Wq[(kk + 2) * DN + col];
        const float wq3 = Wq[(kk + 3) * DN + col];
        const float wk0 = Wk[(kk + 0) * DN + col];
        const float wk1 = Wk[(kk + 1) * DN + col];
        const float wk2 = Wk[(kk + 2) * DN + col];
        const float wk3 = Wk[(kk + 3) * DN + col];
        const float wv0 = Wv[(kk + 0) * DN + col];
        const float wv1 = Wv[(kk + 1) * DN + col];
        const float wv2 = Wv[(kk + 2) * DN + col];
        const float wv3 = Wv[(kk + 3) * DN + col];
#pragma unroll
        for (int n = 0; n < 8; n++) {
            aq[n] += xv[n].x * wq0 + xv[n].y * wq1 + xv[n].z * wq2 + xv[n].w * wq3;
            ak[n] += xv[n].x * wk0 + xv[n].y * wk1 + xv[n].z * wk2 + xv[n].w * wk3;
            av[n] += xv[n].x * wv0 + xv[n].y * wv1 + xv[n].z * wv2 + xv[n].w * wv3;
        }
    }
#pragma unroll
    for (int n = 0; n < 8; n++) {
        const size_t r = (size_t)(nb + g8 + n) * DN + col;
        Qn[r] = aq[n]; Kn[r] = ak[n]; Vn[r] = av[n];
    }

    if (Qt != nullptr) {
        // ---- phase 2: Qt table. Reuse xs as q_lds. ----
        __syncthreads();                    // all reads of xs done
#pragma unroll
        for (int n = 0; n < 8; n++) xs[g8 + n][col] = aq[n];
        __syncthreads();

        // thread owns flat combos f = 2t, 2t+1 (f = h*64+k); reads W once,
        // reuses across all 16 nodes (WkB traffic = 32KB/block).
        const int f0 = 2 * t;               // 0..510, even
        const int h  = f0 >> 6;             // 0..7
        const int k0 = f0 & 63;
        const float* __restrict__ WkB = Wk + 128 * DN;
        float w0[16], w1[16];
#pragma unroll
        for (int m4 = 0; m4 < 16; m4 += 4) {
            *(float4*)&w0[m4] = *(const float4*)(WkB + (size_t)k0 * DN + h * 16 + m4);
            *(float4*)&w1[m4] = *(const float4*)(WkB + (size_t)(k0 + 1) * DN + h * 16 + m4);
        }
#pragma unroll
        for (int n = 0; n < 16; n++) {
            float s0 = 0.f, s1 = 0.f;
#pragma unroll
            for (int m4 = 0; m4 < 16; m4 += 4) {
                const float4 qv = *(const float4*)&xs[n][h * 16 + m4];
                s0 += qv.x * w0[m4]   + qv.y * w0[m4+1] + qv.z * w0[m4+2] + qv.w * w0[m4+3];
                s1 += qv.x * w1[m4]   + qv.y * w1[m4+1] + qv.z * w1[m4+2] + qv.w * w1[m4+3];
            }
            *(float2*)(Qt + (size_t)(nb + n) * 512 + f0) = make_float2(s0, s1);
        }
    }
}

// ---------------------------------------------------------------------------
// K1b (fallback tier): only Qn -> d_out (fp32)
// ---------------------------------------------------------------------------
__global__ __launch_bounds__(256) void node_proj_q(
    const float* __restrict__ nf,
    const float* __restrict__ Wq, const float* __restrict__ bq,
    float* __restrict__ Qn)
{
    __shared__ alignas(16) float xs[128][8];
    const int t = threadIdx.x;
    const int nb = blockIdx.x * 8;
    {
        const int node = t >> 5;
        const int k0 = (t & 31) * 4;
        const float4 x4 = *(const float4*)(nf + (size_t)(nb + node) * DN + k0);
        xs[k0 + 0][node] = x4.x;
        xs[k0 + 1][node] = x4.y;
        xs[k0 + 2][node] = x4.z;
        xs[k0 + 3][node] = x4.w;
    }
    __syncthreads();

    const int col = t & 127;
    const int grp = t >> 7;
    float aq[4];
    const float bqv = bq[col];
#pragma unroll
    for (int i = 0; i < 4; i++) aq[i] = bqv;

#pragma unroll 4
    for (int k = 0; k < 128; k++) {
        const float wq = Wq[k * DN + col];
        const float4 x = *(const float4*)&xs[k][grp * 4];
        aq[0] += x.x * wq; aq[1] += x.y * wq; aq[2] += x.z * wq; aq[3] += x.w * wq;
    }
#pragma unroll
    for (int i = 0; i < 4; i++)
        Qn[(size_t)(nb + grp * 4 + i) * DN + col] = aq[i];
}

// ---------------------------------------------------------------------------
// CSR build: histogram, 3-kernel exclusive scan, scatter -> epack{edge,src}.
// ---------------------------------------------------------------------------
__global__ __launch_bounds__(256) void edge_hist(
    const int* __restrict__ eidx, int* __restrict__ cnt)
{
    const int e = blockIdx.x * 256 + threadIdx.x;   // grid exact: NED/256
    atomicAdd(&cnt[eidx[NED + e]], 1);
}

#define SCAN_NB ((NND + 255) / 256)   // 196

__global__ __launch_bounds__(256) void scanA(
    const int* __restrict__ cnt, int* __restrict__ partial)
{
    const int idx = blockIdx.x * 256 + threadIdx.x;
    int v = (idx < NND) ? cnt[idx] : 0;
#pragma unroll
    for (int off = 1; off < 64; off <<= 1) v += __shfl_xor(v, off);
    __shared__ int wsum[4];
    if ((threadIdx.x & 63) == 0) wsum[threadIdx.x >> 6] = v;
    __syncthreads();
    if (threadIdx.x == 0)
        partial[blockIdx.x] = wsum[0] + wsum[1] + wsum[2] + wsum[3];
}

__global__ __launch_bounds__(256) void scanB(int* __restrict__ partial)
{
    __shared__ int s[256];
    const int t = threadIdx.x;
    const int v = (t < SCAN_NB) ? partial[t] : 0;
    s[t] = v;
    __syncthreads();
    for (int off = 1; off < 256; off <<= 1) {
        const int u = (t >= off) ? s[t - off] : 0;
        __syncthreads();
        s[t] += u;
        __syncthreads();
    }
    if (t < SCAN_NB) partial[t] = s[t] - v;   // exclusive
}

__global__ __launch_bounds__(256) void scanC(
    const int* __restrict__ cnt, const int* __restrict__ partial,
    int* __restrict__ offs)
{
    __shared__ int s[256];
    const int t = threadIdx.x;
    const int idx = blockIdx.x * 256 + t;
    const int v = (idx < NND) ? cnt[idx] : 0;
    s[t] = v;
    __syncthreads();
    for (int off = 1; off < 256; off <<= 1) {
        const int u = (t >= off) ? s[t - off] : 0;
        __syncthreads();
        s[t] += u;
        __syncthreads();
    }
    if (idx < NND) offs[idx] = partial[blockIdx.x] + s[t] - v;   // exclusive
}

// bumps offs in place: afterwards offs[n] == segment END (exclusive), beg = end-cnt[n]
__global__ __launch_bounds__(256) void edge_scatter(
    const int* __restrict__ eidx, int* __restrict__ offs, int2* __restrict__ epack)
{
    const int e = blockIdx.x * 256 + threadIdx.x;   // grid exact: NED/256
    const int pos = atomicAdd(&offs[eidx[NED + e]], 1);
    epack[pos] = make_int2(e, eidx[e]);
}

// ---------------------------------------------------------------------------
// K2 (fast tier): one wave per target node over its CSR segment.
//   logit[e,h] = 0.25*( q.Kn[src] + sum_k Qt[h,k]*ef[e,k] )
//   o = ( sum_e p*Vn[src] + G @ WvB ) / sum_e p,  G[h,k] = sum_e p[e,h]*ef[e,k]
// Qtab != nullptr: qt[8] is a 32B coalesced table load (flat idx = l*8+i)
// instead of the 64-iter shfl-reduce prologue (saves ~40% of wave instrs
// and 32KB/wave of L1 WkB traffic).
// ---------------------------------------------------------------------------
__global__ __launch_bounds__(256) void edge_aggregate(
    const float* __restrict__ ef,
    const int* __restrict__ cnt, const int* __restrict__ offs,
    const int2* __restrict__ epack,
    const float* __restrict__ Wk, const float* __restrict__ Wv,
    const float* __restrict__ Kn, const float* __restrict__ Vn,
    const float* __restrict__ Qtab,
    float* qo)
{
    __shared__ alignas(16) float efs[4][8][64];   // [wave][edge][k]
    const int t = threadIdx.x;
    const int w = t >> 6;
    const int l = t & 63;
    const int j = l & 7;
    const int node = blockIdx.x * 4 + w;          // grid exact: NND/4

    const int end = offs[node];                   // post-scatter: segment end
    const int beg = end - cnt[node];

    const float* __restrict__ WkB = Wk + 128 * DN;   // edge rows of Wk [192,128]
    const float* __restrict__ WvB = Wv + 128 * DN;

    const float2 q2 = *(const float2*)(qo + (size_t)node * DN + 2 * l);

    float qt[8];
    if (Qtab != nullptr) {
        const float4 qa = *(const float4*)(Qtab + (size_t)node * 512 + l * 8);
        const float4 qb = *(const float4*)(Qtab + (size_t)node * 512 + l * 8 + 4);
        qt[0] = qa.x; qt[1] = qa.y; qt[2] = qa.z; qt[3] = qa.w;
        qt[4] = qb.x; qt[5] = qb.y; qt[6] = qb.z; qt[7] = qb.w;
    } else {
        // fallback prologue: Qt[h, j*8+i] via shfl-reduce over head cols
#pragma unroll
        for (int i = 0; i < 8; i++) qt[i] = 0.f;
#pragma unroll 16
        for (int k = 0; k < 64; k++) {
            const float2 wk2 = *(const float2*)(WkB + k * DN + 2 * l);
            float part = q2.x * wk2.x + q2.y * wk2.y;
            part += __shfl_xor(part, 1);
            part += __shfl_xor(part, 2);
            part += __shfl_xor(part, 4);
            if (j == (k >> 3)) qt[k & 7] = part;
        }
    }

    float acc0 = 0.f, acc1 = 0.f, segacc = 0.f;
    float gt[8];
#pragma unroll
    for (int i = 0; i < 8; i++) gt[i] = 0.f;

    for (int base = beg; base < end; base += 8) {
        const int myE = min(base + (l >> 3), end - 1);   // clamp padded slots
        const int2 ep = nt_load2i(&epack[myE]);
        // stage ef chunk: lane stages its edge's k-slice j*8..j*8+7
        const float4 A = nt_load4(ef + (size_t)ep.x * DE + j * 8);
        const float4 B = nt_load4(ef + (size_t)ep.x * DE + j * 8 + 4);
        *(float4*)&efs[w][l >> 3][j * 8]     = A;
        *(float4*)&efs[w][l >> 3][j * 8 + 4] = B;

#pragma unroll
        for (int e = 0; e < 8; e++) {
            const int se = __builtin_amdgcn_readlane(ep.y, e * 8);
            const float4 efA = *(const float4*)&efs[w][e][j * 8];
            const float4 efB = *(const float4*)&efs[w][e][j * 8 + 4];
            const float2 kn2 = *(const float2*)(Kn + (size_t)se * DN + 2 * l);
            float part = q2.x * kn2.x + q2.y * kn2.y
                       + efA.x * qt[0] + efA.y * qt[1] + efA.z * qt[2] + efA.w * qt[3]
                       + efB.x * qt[4] + efB.y * qt[5] + efB.z * qt[6] + efB.w * qt[7];
            part += __shfl_xor(part, 1);
            part += __shfl_xor(part, 2);
            part += __shfl_xor(part, 4);          // logit[e,h] on 8-lane head group
            const float arg = fminf(fmaxf(part * 0.25f, -60.f), 60.f);  // 1/sqrt(16)
            const float p = (base + e < end) ? __expf(arg) : 0.f;       // mask pads
            const float2 vn2 = *(const float2*)(Vn + (size_t)se * DN + 2 * l);
            acc0 += p * vn2.x;
            acc1 += p * vn2.y;
            segacc += p;
            gt[0] += p * efA.x; gt[1] += p * efA.y; gt[2] += p * efA.z; gt[3] += p * efA.w;
            gt[4] += p * efB.x; gt[5] += p * efB.y; gt[6] += p * efB.z; gt[7] += p * efB.w;
        }
    }

    // ---- epilogue: o_edge = G @ WvB (G slices broadcast via shfl) ----
    float oe0 = 0.f, oe1 = 0.f;
#pragma unroll 16
    for (int k = 0; k < 64; k++) {
        const float g = __shfl(gt[k & 7], (l & 56) | (k >> 3));
        const float2 wv2 = *(const float2*)(WvB + k * DN + 2 * l);
        oe0 += g * wv2.x;
        oe1 += g * wv2.y;
    }
    acc0 += oe0;
    acc1 += oe1;

    const float r = (segacc > 0.f) ? 1.f / segacc : 0.f;   // deg==0 -> zeros
    float* orow = qo + (size_t)node * DN + 2 * l;
    orow[0] = sane(acc0 * r);
    orow[1] = sane(acc1 * r);
}

// ---------------------------------------------------------------------------
// K2b (fallback tier, needs only 27.2MB ws): recompute full K/V per edge,
// scatter with atomics. (unchanged)
// ---------------------------------------------------------------------------
__global__ __launch_bounds__(256) void edge_pass_full(
    const float* __restrict__ nf, const float* __restrict__ ef,
    const int* __restrict__ eidx,
    const float* __restrict__ Wk, const float* __restrict__ bk,
    const float* __restrict__ Wv, const float* __restrict__ bv,
    const float* __restrict__ Qn,
    float* __restrict__ o_un, float* __restrict__ seg)
{
    __shared__ alignas(16) float kvs[4][192][4];
    const int t = threadIdx.x;
    const int w = t >> 6;
    const int l = t & 63;
    const int eb = blockIdx.x * 16 + w * 4;

    int src[4], tgt[4];
#pragma unroll
    for (int e = 0; e < 4; e++) {
        src[e] = eidx[eb + e];
        tgt[e] = eidx[NED + eb + e];
    }

#pragma unroll
    for (int it = 0; it < 3; it++) {
        const int idx = it * 64 + l;
        const int e = idx / 48;
        const int pos = (idx % 48) * 4;
        const float* p = (pos < 128)
            ? nf + (size_t)src[e] * DN + pos
            : ef + (size_t)(eb + e) * DE + (pos - 128);
        const float4 x4 = *(const float4*)p;
        kvs[w][pos + 0][e] = x4.x;
        kvs[w][pos + 1][e] = x4.y;
        kvs[w][pos + 2][e] = x4.z;
        kvs[w][pos + 3][e] = x4.w;
    }
    __syncthreads();

    const float bk0 = bk[2 * l], bk1 = bk[2 * l + 1];
    const float bv0 = bv[2 * l], bv1 = bv[2 * l + 1];
    float accK[4][2] = {{bk0,bk1},{bk0,bk1},{bk0,bk1},{bk0,bk1}};
    float accV[4][2] = {{bv0,bv1},{bv0,bv1},{bv0,bv1},{bv0,bv1}};

#pragma unroll 4
    for (int k = 0; k < DKV; k++) {
        const float4 e4 = *(const float4*)&kvs[w][k][0];
        const float2 wk2 = *(const float2*)(Wk + k * DN + 2 * l);
        const float2 wv2 = *(const float2*)(Wv + k * DN + 2 * l);
        accK[0][0] += e4.x * wk2.x; accK[0][1] += e4.x * wk2.y;
        accK[1][0] += e4.y * wk2.x; accK[1][1] += e4.y * wk2.y;
        accK[2][0] += e4.z * wk2.x; accK[2][1] += e4.z * wk2.y;
        accK[3][0] += e4.w * wk2.x; accK[3][1] += e4.w * wk2.y;
        accV[0][0] += e4.x * wv2.x; accV[0][1] += e4.x * wv2.y;
        accV[1][0] += e4.y * wv2.x; accV[1][1] += e4.y * wv2.y;
        accV[2][0] += e4.z * wv2.x; accV[2][1] += e4.z * wv2.y;
        accV[3][0] += e4.w * wv2.x; accV[3][1] += e4.w * wv2.y;
    }

    const int h = l >> 3;
#pragma unroll
    for (int e = 0; e < 4; e++) {
        const float2 q2 = *(const float2*)(Qn + (size_t)tgt[e] * DN + 2 * l);
        float part = q2.x * accK[e][0] + q2.y * accK[e][1];
        part += __shfl_xor(part, 1);
        part += __shfl_xor(part, 2);
        part += __shfl_xor(part, 4);
        float arg = fminf(fmaxf(part * 0.25f, -60.f), 60.f);
        const float p = __expf(arg);

        atomicAdd(&o_un[(size_t)tgt[e] * DN + 2 * l],     p * accV[e][0]);
        atomicAdd(&o_un[(size_t)tgt[e] * DN + 2 * l + 1], p * accV[e][1]);
        if ((l & 7) == 0) atomicAdd(&seg[tgt[e] * NH + h], p);
    }
}

// ---------------------------------------------------------------------------
// K3: out = sanitize(o / seg) @ Wo + bo. seg == nullptr -> o already
// normalized. 16 nodes/block; xs[16][128]; weight load amortized over 8 nodes.
// ---------------------------------------------------------------------------
__global__ __launch_bounds__(256) void out_proj(
    const float* o_un, const float* __restrict__ seg,
    const float* __restrict__ Wo, const float* __restrict__ bo,
    float* out)
{
    __shared__ alignas(16) float xs[16][128];
    const int t = threadIdx.x;
    const int nb = blockIdx.x * 16;
#pragma unroll
    for (int s = 0; s < 2; s++) {
        const int idx = s * 256 + t;
        const int node = idx >> 5;          // 0..15
        const int k0 = (idx & 31) * 4;      // same head for all 4 elems
        const float4 v = *(const float4*)(o_un + (size_t)(nb + node) * DN + k0);
        float r = 1.f;
        if (seg) {
            const float sv = seg[(nb + node) * NH + (k0 >> 4)];
            r = (sv > 0.f) ? 1.f / sv : 0.f;
        }
        float4 o4;
        o4.x = sane(v.x * r);
        o4.y = sane(v.y * r);
        o4.z = sane(v.z * r);
        o4.w = sane(v.w * r);
        *(float4*)&xs[node][k0] = o4;
    }
    __syncthreads();

    const int col = t & 127;
    const int g8 = (t >> 7) * 8;
    float acc[8];
    const float b = bo[col];
#pragma unroll
    for (int n = 0; n < 8; n++) acc[n] = b;

#pragma unroll 2
    for (int kk = 0; kk < 128; kk += 4) {
        float4 xv[8];
#pragma unroll
        for (int n = 0; n < 8; n++) xv[n] = *(const float4*)&xs[g8 + n][kk];
        const float w0 = Wo[(kk + 0) * DN + col];
        const float w1 = Wo[(kk + 1) * DN + col];
        const float w2 = Wo[(kk + 2) * DN + col];
        const float w3 = Wo[(kk + 3) * DN + col];
#pragma unroll
        for (int n = 0; n < 8; n++)
            acc[n] += xv[n].x * w0 + xv[n].y * w1 + xv[n].z * w2 + xv[n].w * w3;
    }
#pragma unroll
    for (int n = 0; n < 8; n++)
        out[(size_t)(nb + g8 + n) * DN + col] = acc[n];
}

// ---------------------------------------------------------------------------
extern "C" void kernel_launch(void* const* d_in, const int* in_sizes, int n_in,
                              void* d_out, int out_size, void* d_ws, size_t ws_size,
                              hipStream_t stream) {
    const float* nf   = (const float*)d_in[0];
    const float* ef   = (const float*)d_in[1];
    const int*   eidx = (const int*)d_in[2];
    const float* Wq   = (const float*)d_in[3];
    const float* bq   = (const float*)d_in[4];
    const float* Wk   = (const float*)d_in[5];
    const float* bk   = (const float*)d_in[6];
    const float* Wv   = (const float*)d_in[7];
    const float* bv   = (const float*)d_in[8];
    const float* Wo   = (const float*)d_in[9];
    const float* bo   = (const float*)d_in[10];
    float* out = (float*)d_out;

    // Qn lives in d_out; edge_aggregate overwrites it in place with normalized o,
    // out_proj then overwrites with the final output.
    float* Qn = out;

    const size_t tabBytes = (size_t)NND * DN * sizeof(float);                  // 25.6 MB
    const size_t csrBytes = 2 * tabBytes
                          + ((size_t)2 * NND + 2 * NED + SCAN_NB) * sizeof(int); // ~58 MB
    const size_t qtBytes  = (size_t)NND * 512 * sizeof(float);                 // 102.4 MB
    const size_t accBytes = tabBytes + (size_t)NND * NH * sizeof(float);       // 27.2 MB

    if (ws_size >= csrBytes) {
        float* Kn     = (float*)d_ws;
        float* Vn     = Kn + (size_t)NND * DN;
        int*   cnt    = (int*)(Vn + (size_t)NND * DN);
        int*   offs   = cnt + NND;
        int2*  epack  = (int2*)(offs + NND);        // 8B-aligned
        int*   partial= (int*)(epack + NED);
        float* Qt     = (ws_size >= csrBytes + qtBytes)
                      ? (float*)(partial + SCAN_NB) : nullptr;
        (void)hipMemsetAsync(cnt, 0, NND * sizeof(int), stream);
        node_proj_qkv<<<NND / 16, 256, 0, stream>>>(nf, Wq, bq, Wk, bk, Wv, bv,
                                                    Qn, Kn, Vn, Qt);
        edge_hist<<<NED / 256, 256, 0, stream>>>(eidx, cnt);
        scanA<<<SCAN_NB, 256, 0, stream>>>(cnt, partial);
        scanB<<<1, 256, 0, stream>>>(partial);
        scanC<<<SCAN_NB, 256, 0, stream>>>(cnt, partial, offs);
        edge_scatter<<<NED / 256, 256, 0, stream>>>(eidx, offs, epack);
        edge_aggregate<<<NND / 4, 256, 0, stream>>>(ef, cnt, offs, epack,
                                                    Wk, Wv, Kn, Vn, Qt, Qn);
        out_proj<<<NND / 16, 256, 0, stream>>>(Qn, nullptr, Wo, bo, out);
    } else {
        float* o_un = (float*)d_ws;
        float* seg  = o_un + (size_t)NND * DN;
        (void)hipMemsetAsync(o_un, 0, accBytes, stream);
        node_proj_q<<<NND / 8, 256, 0, stream>>>(nf, Wq, bq, Qn);
        edge_pass_full<<<NED / 16, 256, 0, stream>>>(nf, ef, eidx, Wk, bk, Wv, bv, Qn, o_un, seg);
        out_proj<<<NND / 16, 256, 0, stream>>>(o_un, seg, Wo, bo, out);
    }
}